// Round 11
// baseline (207.293 us; speedup 1.0000x reference)
//
#include <hip/hip_runtime.h>
#include <hip/hip_bf16.h>
#include <math.h>

#define WEPS 1e-5f
#define WSCALE 0.125f
#define QSCALE 0.1803368801111244f   // 0.125 * log2(e)

enum { EPI_NONE=0, EPI_BIAS=1, EPI_BN_RELU=2 };

typedef __attribute__((ext_vector_type(8))) short bf16x8;
typedef __attribute__((ext_vector_type(4))) float f32x4;

static __device__ inline unsigned short f2bf(float f) {
    __hip_bfloat16 h = __float2bfloat16(f);
    return *(unsigned short*)&h;
}
// native 2^x (v_exp_f32 computes exp2)
static __device__ inline float exp2_fast(float x) {
    float r;
    asm("v_exp_f32 %0, %1" : "=v"(r) : "v"(x));
    return r;
}
// packed f32x2 -> bf16x2 (lo = a, hi = b)
static __device__ inline unsigned cvt_pk_bf16(float a, float b) {
    unsigned r;
    asm("v_cvt_pk_bf16_f32 %0, %1, %2" : "=v"(r) : "v"(a), "v"(b));
    return r;
}
// XCD-aware chunked swizzle (gridDim.x % 8 == 0)
static __device__ inline int xcd_swizzle_id() {
    int id = blockIdx.x;
    int q = gridDim.x >> 3;
    return (id & 7) * q + (id >> 3);
}

// swizzled LDS 16B fragment read: 128B rows, byte ^= (row&7)<<4
static __device__ inline bf16x8 lds_frag(const unsigned short* base, int row, int inner) {
    int byte = row * 128 + (inner ^ ((row & 7) << 4));
    return *(const bf16x8*)((const char*)base + byte);
}
// swizzled LDS 16B fragment read: 256B rows, byte ^= (row&15)<<4
static __device__ inline bf16x8 lds_frag256(const unsigned short* base, int row, int inner) {
    int byte = row * 256 + (inner ^ ((row & 15) << 4));
    return *(const bf16x8*)((const char*)base + byte);
}

// ================= bf16 MFMA GEMM, 128x128 tile, dbuf + XCD swizzle =================
// C[M,N] = oscale*A@Bt^T. 1D grid = nbx*(M/128), single barrier per K-iter.
template<int EPI, int OBF16>
__launch_bounds__(256)
__global__ void gemm_bf16(const __hip_bfloat16* __restrict__ A, int lda,
                          const __hip_bfloat16* __restrict__ Bt, int K,
                          void* __restrict__ Cv, int ldc, int N, int nbx,
                          const float* __restrict__ bias,
                          const float* __restrict__ bn_g,
                          const float* __restrict__ bn_b,
                          float oscale)
{
    __shared__ unsigned short As[2][8192];
    __shared__ unsigned short Bs[2][8192];
    const int tid = threadIdx.x;
    const int lane = tid & 63, wv = tid >> 6;
    const int g = lane >> 4, l16 = lane & 15;
    const int wr = wv >> 1, wc = wv & 1;
    const int w = xcd_swizzle_id();
    const int bm = (w / nbx) << 7;
    const int bn = (w % nbx) << 7;

    int swb[4];
    const __hip_bfloat16 *Ap[4], *Bp[4];
    bool bok[4];
    #pragma unroll
    for (int it = 0; it < 4; it++) {
        int idx = tid + (it << 8);
        int row = idx >> 3, seg = idx & 7;
        swb[it] = row * 128 + ((seg << 4) ^ ((row & 7) << 4));
        Ap[it] = A + (size_t)(bm + row) * lda + (seg << 3);
        int col = bn + row;
        bok[it] = col < N;
        Bp[it] = Bt + (size_t)(bok[it] ? col : 0) * K + (seg << 3);
    }
    f32x4 acc[4][4];
    #pragma unroll
    for (int i = 0; i < 4; i++)
        #pragma unroll
        for (int j = 0; j < 4; j++)
            #pragma unroll
            for (int r = 0; r < 4; r++) acc[i][j][r] = 0.f;

    // prologue: stage K-tile 0 into buffer 0
    #pragma unroll
    for (int it = 0; it < 4; it++) {
        *(float4*)((char*)As[0] + swb[it]) = *(const float4*)(Ap[it]);
        float4 bv = make_float4(0.f,0.f,0.f,0.f);
        if (bok[it]) bv = *(const float4*)(Bp[it]);
        *(float4*)((char*)Bs[0] + swb[it]) = bv;
    }
    __syncthreads();

    int cur = 0;
    const int niter = K >> 6;
    for (int t = 0; t < niter; t++) {
        float4 ra[4], rb[4];
        const bool has_next = (t + 1 < niter);
        if (has_next) {
            int kb = (t + 1) << 6;
            #pragma unroll
            for (int it = 0; it < 4; it++) {
                ra[it] = *(const float4*)(Ap[it] + kb);
                rb[it] = make_float4(0.f,0.f,0.f,0.f);
                if (bok[it]) rb[it] = *(const float4*)(Bp[it] + kb);
            }
        }
        #pragma unroll
        for (int ks = 0; ks < 2; ks++) {
            bf16x8 af[4], bfr[4];
            #pragma unroll
            for (int i = 0; i < 4; i++)
                af[i] = lds_frag(As[cur], (wr<<6) + (i<<4) + l16, (ks<<6) + (g<<4));
            #pragma unroll
            for (int j = 0; j < 4; j++)
                bfr[j] = lds_frag(Bs[cur], (wc<<6) + (j<<4) + l16, (ks<<6) + (g<<4));
            #pragma unroll
            for (int i = 0; i < 4; i++)
                #pragma unroll
                for (int j = 0; j < 4; j++)
                    acc[i][j] = __builtin_amdgcn_mfma_f32_16x16x32_bf16(af[i], bfr[j], acc[i][j], 0, 0, 0);
        }
        if (has_next) {
            #pragma unroll
            for (int it = 0; it < 4; it++) {
                *(float4*)((char*)As[cur^1] + swb[it]) = ra[it];
                *(float4*)((char*)Bs[cur^1] + swb[it]) = rb[it];
            }
        }
        __syncthreads();
        cur ^= 1;
    }
    const float bn_s = 0.99999500003749968f;
    #pragma unroll
    for (int i = 0; i < 4; i++) {
        int m = bm + (wr<<6) + (i<<4) + (g<<2);
        #pragma unroll
        for (int j = 0; j < 4; j++) {
            int c = bn + (wc<<6) + (j<<4) + l16;
            if (c >= N) continue;
            float bi = (EPI != EPI_NONE) ? bias[c] : 0.f;
            float sc = 1.f, bb = 0.f;
            if (EPI == EPI_BN_RELU) { sc = bn_g[c] * bn_s; bb = bn_b[c]; }
            #pragma unroll
            for (int r = 0; r < 4; r++) {
                float t = acc[i][j][r] * oscale + bi;
                if (EPI == EPI_BN_RELU) t = fmaxf(t * sc + bb, 0.f);
                if (OBF16) ((__hip_bfloat16*)Cv)[(size_t)(m+r)*ldc + c] = __float2bfloat16(t);
                else       ((float*)Cv)[(size_t)(m+r)*ldc + c] = t;
            }
        }
    }
}

// ================= fused head GEMM: xb @ [sqkv|wq|reduce], dbuf + XCD swizzle =======
// Grid 1152 (1D). bm = w/9, bn = w%9. K=512 (8 iters).
__launch_bounds__(256)
__global__ void gemmX(const __hip_bfloat16* __restrict__ A,
                      const __hip_bfloat16* __restrict__ Bt,
                      __hip_bfloat16* __restrict__ qkvb,
                      __hip_bfloat16* __restrict__ qbw,
                      float* __restrict__ rbuf,
                      const float* __restrict__ red_b,
                      const float* __restrict__ rbn_g,
                      const float* __restrict__ rbn_b)
{
    __shared__ unsigned short As[2][8192];
    __shared__ unsigned short Bs[2][8192];
    const int tid = threadIdx.x;
    const int lane = tid & 63, wv = tid >> 6;
    const int g = lane >> 4, l16 = lane & 15;
    const int wr = wv >> 1, wc = wv & 1;
    const int w = xcd_swizzle_id();
    const int bm = (w / 9) << 7;
    const int bn = (w % 9) << 7;

    int swb[4];
    const __hip_bfloat16 *Ap[4], *Bp[4];
    bool bok[4];
    #pragma unroll
    for (int it = 0; it < 4; it++) {
        int idx = tid + (it << 8);
        int row = idx >> 3, seg = idx & 7;
        swb[it] = row * 128 + ((seg << 4) ^ ((row & 7) << 4));
        Ap[it] = A + (size_t)(bm + row) * 512 + (seg << 3);
        int col = bn + row;
        bok[it] = col < 1088;
        Bp[it] = Bt + (size_t)(bok[it] ? col : 0) * 512 + (seg << 3);
    }
    f32x4 acc[4][4];
    #pragma unroll
    for (int i = 0; i < 4; i++)
        #pragma unroll
        for (int j = 0; j < 4; j++)
            #pragma unroll
            for (int r = 0; r < 4; r++) acc[i][j][r] = 0.f;

    #pragma unroll
    for (int it = 0; it < 4; it++) {
        *(float4*)((char*)As[0] + swb[it]) = *(const float4*)(Ap[it]);
        float4 bv = make_float4(0.f,0.f,0.f,0.f);
        if (bok[it]) bv = *(const float4*)(Bp[it]);
        *(float4*)((char*)Bs[0] + swb[it]) = bv;
    }
    __syncthreads();

    int cur = 0;
    for (int t = 0; t < 8; t++) {
        float4 ra[4], rb[4];
        const bool has_next = (t < 7);
        if (has_next) {
            int kb = (t + 1) << 6;
            #pragma unroll
            for (int it = 0; it < 4; it++) {
                ra[it] = *(const float4*)(Ap[it] + kb);
                rb[it] = make_float4(0.f,0.f,0.f,0.f);
                if (bok[it]) rb[it] = *(const float4*)(Bp[it] + kb);
            }
        }
        #pragma unroll
        for (int ks = 0; ks < 2; ks++) {
            bf16x8 af[4], bfr[4];
            #pragma unroll
            for (int i = 0; i < 4; i++)
                af[i] = lds_frag(As[cur], (wr<<6) + (i<<4) + l16, (ks<<6) + (g<<4));
            #pragma unroll
            for (int j = 0; j < 4; j++)
                bfr[j] = lds_frag(Bs[cur], (wc<<6) + (j<<4) + l16, (ks<<6) + (g<<4));
            #pragma unroll
            for (int i = 0; i < 4; i++)
                #pragma unroll
                for (int j = 0; j < 4; j++)
                    acc[i][j] = __builtin_amdgcn_mfma_f32_16x16x32_bf16(af[i], bfr[j], acc[i][j], 0, 0, 0);
        }
        if (has_next) {
            #pragma unroll
            for (int it = 0; it < 4; it++) {
                *(float4*)((char*)As[cur^1] + swb[it]) = ra[it];
                *(float4*)((char*)Bs[cur^1] + swb[it]) = rb[it];
            }
        }
        __syncthreads();
        cur ^= 1;
    }
    const float bn_s = 0.99999500003749968f;
    #pragma unroll
    for (int i = 0; i < 4; i++) {
        int m = bm + (wr<<6) + (i<<4) + (g<<2);
        #pragma unroll
        for (int j = 0; j < 4; j++) {
            int c = bn + (wc<<6) + (j<<4) + l16;
            if (c >= 1088) continue;
            if (c < 768) {
                #pragma unroll
                for (int r = 0; r < 4; r++)
                    qkvb[(size_t)(m+r)*768 + c] = __float2bfloat16(acc[i][j][r]);
            } else if (c < 1024) {
                int c2 = c - 768;
                #pragma unroll
                for (int r = 0; r < 4; r++)
                    qbw[(size_t)(m+r)*256 + c2] = __float2bfloat16(acc[i][j][r] * QSCALE);
            } else {
                int c2 = c - 1024;
                float sc = rbn_g[c2] * bn_s, bb = rbn_b[c2], bi = red_b[c2];
                #pragma unroll
                for (int r = 0; r < 4; r++)
                    rbuf[(size_t)(m+r)*64 + c2] = fmaxf((acc[i][j][r] + bi) * sc + bb, 0.f);
            }
        }
    }
}

// ================= kv GEMM, 64x64 tile dbuf: K row-major + V transposed out =========
__launch_bounds__(256)
__global__ void gemm64_kv(const __hip_bfloat16* __restrict__ A,
                          const __hip_bfloat16* __restrict__ Bt,
                          __hip_bfloat16* __restrict__ kbo,   // [16][1024][64]
                          __hip_bfloat16* __restrict__ vto,   // [16][64][1024]
                          const float* __restrict__ bias)
{
    __shared__ unsigned short As[2][4096];
    __shared__ unsigned short Bs[2][4096];
    const int tid = threadIdx.x;
    const int lane = tid & 63, wv = tid >> 6;
    const int g = lane >> 4, l16 = lane & 15;
    const int wr = wv >> 1, wc = wv & 1;
    const int bm = blockIdx.y << 6;
    const int bn = blockIdx.x << 6;

    int swb[2];
    const __hip_bfloat16 *Ap[2], *Bp[2];
    #pragma unroll
    for (int it = 0; it < 2; it++) {
        int idx = tid + (it << 8);
        int row = idx >> 3, seg = idx & 7;
        swb[it] = row * 128 + ((seg << 4) ^ ((row & 7) << 4));
        Ap[it] = A  + (size_t)(bm + row) * 256 + (seg << 3);
        Bp[it] = Bt + (size_t)(bn + row) * 256 + (seg << 3);
    }
    f32x4 acc[2][2];
    #pragma unroll
    for (int i = 0; i < 2; i++)
        #pragma unroll
        for (int j = 0; j < 2; j++)
            #pragma unroll
            for (int r = 0; r < 4; r++) acc[i][j][r] = 0.f;

    #pragma unroll
    for (int it = 0; it < 2; it++) {
        *(float4*)((char*)As[0] + swb[it]) = *(const float4*)(Ap[it]);
        *(float4*)((char*)Bs[0] + swb[it]) = *(const float4*)(Bp[it]);
    }
    __syncthreads();

    int cur = 0;
    for (int t = 0; t < 4; t++) {
        float4 ra[2], rb[2];
        const bool has_next = (t < 3);
        if (has_next) {
            #pragma unroll
            for (int it = 0; it < 2; it++) {
                ra[it] = *(const float4*)(Ap[it] + ((t + 1) << 6));
                rb[it] = *(const float4*)(Bp[it] + ((t + 1) << 6));
            }
        }
        #pragma unroll
        for (int ks = 0; ks < 2; ks++) {
            bf16x8 af[2], bfr[2];
            #pragma unroll
            for (int i = 0; i < 2; i++)
                af[i] = lds_frag(As[cur], (wr<<5) + (i<<4) + l16, (ks<<6) + (g<<4));
            #pragma unroll
            for (int j = 0; j < 2; j++)
                bfr[j] = lds_frag(Bs[cur], (wc<<5) + (j<<4) + l16, (ks<<6) + (g<<4));
            #pragma unroll
            for (int i = 0; i < 2; i++)
                #pragma unroll
                for (int j = 0; j < 2; j++)
                    acc[i][j] = __builtin_amdgcn_mfma_f32_16x16x32_bf16(af[i], bfr[j], acc[i][j], 0, 0, 0);
        }
        if (has_next) {
            #pragma unroll
            for (int it = 0; it < 2; it++) {
                *(float4*)((char*)As[cur^1] + swb[it]) = ra[it];
                *(float4*)((char*)Bs[cur^1] + swb[it]) = rb[it];
            }
        }
        __syncthreads();
        cur ^= 1;
    }

    #pragma unroll
    for (int i = 0; i < 2; i++) {
        int m = bm + (wr<<5) + (i<<4) + (g<<2);
        int bimg = m >> 10, tkn0 = m & 1023;
        #pragma unroll
        for (int j = 0; j < 2; j++) {
            int c = bn + (wc<<5) + (j<<4) + l16;
            if (c < 256) {          // K: [bh][token][d]
                int wh = c >> 6, d0 = c & 63;
                __hip_bfloat16* kp = kbo + (((size_t)((bimg<<2)+wh)) << 16) + (size_t)tkn0*64 + d0;
                #pragma unroll
                for (int r = 0; r < 4; r++)
                    kp[r*64] = __float2bfloat16(acc[i][j][r] + bias[c]);
            } else {                // V: [bh][d][token]
                int c2 = c - 256;
                int wh = c2 >> 6, d = c2 & 63;
                float bi = bias[256 + c2];
                ushort4 h;
                h.x = f2bf(acc[i][j][0] + bi);
                h.y = f2bf(acc[i][j][1] + bi);
                h.z = f2bf(acc[i][j][2] + bi);
                h.w = f2bf(acc[i][j][3] + bi);
                *(ushort4*)(vto + (((size_t)((bimg<<2)+wh)) << 16) + (size_t)d*1024 + tkn0) = h;
            }
        }
    }
}

// ================= fused wproj GEMM, 128x128 dbuf + XCD swizzle =====================
// Grid 256 (1D); bm = w/2, bn = w%2. K=320 (5 iters).
__launch_bounds__(256)
__global__ void gemm_wproj(const __hip_bfloat16* __restrict__ A1,
                           const __hip_bfloat16* __restrict__ A2,
                           const __hip_bfloat16* __restrict__ Bt,  // [256][320]
                           float* __restrict__ C,                  // out+256, ldc=512
                           const float* __restrict__ bias)
{
    __shared__ unsigned short As[2][8192];
    __shared__ unsigned short Bs[2][8192];
    const int tid = threadIdx.x;
    const int lane = tid & 63, wv = tid >> 6;
    const int g = lane >> 4, l16 = lane & 15;
    const int wr = wv >> 1, wc = wv & 1;
    const int w = xcd_swizzle_id();
    const int bm = (w >> 1) << 7;
    const int bn = (w & 1) << 7;

    int srow[4], sseg[4], swb[4];
    const __hip_bfloat16 *Bp[4];
    #pragma unroll
    for (int it = 0; it < 4; it++) {
        int idx = tid + (it << 8);
        srow[it] = idx >> 3; sseg[it] = idx & 7;
        swb[it] = srow[it] * 128 + ((sseg[it] << 4) ^ ((srow[it] & 7) << 4));
        Bp[it] = Bt + (size_t)(bn + srow[it]) * 320 + (sseg[it] << 3);
    }
    f32x4 acc[4][4];
    #pragma unroll
    for (int i = 0; i < 4; i++)
        #pragma unroll
        for (int j = 0; j < 4; j++)
            #pragma unroll
            for (int r = 0; r < 4; r++) acc[i][j][r] = 0.f;

    #pragma unroll
    for (int it = 0; it < 4; it++) {
        *(float4*)((char*)As[0] + swb[it]) =
            *(const float4*)(A1 + (size_t)(bm + srow[it]) * 256 + (sseg[it] << 3));
        *(float4*)((char*)Bs[0] + swb[it]) = *(const float4*)(Bp[it]);
    }
    __syncthreads();

    int cur = 0;
    for (int t = 0; t < 5; t++) {
        float4 ra[4], rb[4];
        const bool has_next = (t < 4);
        if (has_next) {
            int kb = (t + 1) << 6;
            #pragma unroll
            for (int it = 0; it < 4; it++) {
                if (kb < 256)
                    ra[it] = *(const float4*)(A1 + (size_t)(bm + srow[it]) * 256 + kb + (sseg[it] << 3));
                else
                    ra[it] = *(const float4*)(A2 + (size_t)(bm + srow[it]) * 64 + (kb - 256) + (sseg[it] << 3));
                rb[it] = *(const float4*)(Bp[it] + kb);
            }
        }
        #pragma unroll
        for (int ks = 0; ks < 2; ks++) {
            bf16x8 af[4], bfr[4];
            #pragma unroll
            for (int i = 0; i < 4; i++)
                af[i] = lds_frag(As[cur], (wr<<6) + (i<<4) + l16, (ks<<6) + (g<<4));
            #pragma unroll
            for (int j = 0; j < 4; j++)
                bfr[j] = lds_frag(Bs[cur], (wc<<6) + (j<<4) + l16, (ks<<6) + (g<<4));
            #pragma unroll
            for (int i = 0; i < 4; i++)
                #pragma unroll
                for (int j = 0; j < 4; j++)
                    acc[i][j] = __builtin_amdgcn_mfma_f32_16x16x32_bf16(af[i], bfr[j], acc[i][j], 0, 0, 0);
        }
        if (has_next) {
            #pragma unroll
            for (int it = 0; it < 4; it++) {
                *(float4*)((char*)As[cur^1] + swb[it]) = ra[it];
                *(float4*)((char*)Bs[cur^1] + swb[it]) = rb[it];
            }
        }
        __syncthreads();
        cur ^= 1;
    }
    #pragma unroll
    for (int i = 0; i < 4; i++) {
        int m = bm + (wr<<6) + (i<<4) + (g<<2);
        #pragma unroll
        for (int j = 0; j < 4; j++) {
            int c = bn + (wc<<6) + (j<<4) + l16;
            float bi = bias[c];
            #pragma unroll
            for (int r = 0; r < 4; r++)
                C[(size_t)(m+r)*512 + c] = acc[i][j][r] + bi;
        }
    }
}

// ================= 3x3 conv: bf16 MFMA, 64x64 tile, BK=128, double-buffered =====
__launch_bounds__(256)
__global__ void conv3_mfma(const __hip_bfloat16* __restrict__ Xd,
                           const __hip_bfloat16* __restrict__ Wt,
                           float* __restrict__ C,
                           const float* __restrict__ bias,
                           const float* __restrict__ bn_g,
                           const float* __restrict__ bn_b)
{
    __shared__ unsigned short As[2][8192];
    __shared__ unsigned short Bs[2][8192];
    const int tid = threadIdx.x;
    const int lane = tid & 63, wv = tid >> 6;
    const int g = lane >> 4, l16 = lane & 15;
    const int wr = wv >> 1, wc = wv & 1;
    const int bm = blockIdx.y << 6;
    const int bn = blockIdx.x << 6;

    int srow[4], sseg[4], swb[4];
    #pragma unroll
    for (int it = 0; it < 4; it++) {
        int idx = tid + (it << 8);
        srow[it] = idx >> 4;
        sseg[it] = idx & 15;
        swb[it]  = srow[it] * 256 + ((sseg[it] << 4) ^ ((srow[it] & 15) << 4));
    }
    int abase[4], ay[4], ax[4];
    #pragma unroll
    for (int it = 0; it < 4; it++) {
        int m = bm + srow[it];
        int bimg = m >> 10, s = m & 1023;
        ay[it] = s >> 5; ax[it] = s & 31;
        abase[it] = bimg << 10;
    }

    f32x4 acc[2][2];
    #pragma unroll
    for (int i = 0; i < 2; i++)
        #pragma unroll
        for (int j = 0; j < 2; j++)
            #pragma unroll
            for (int r = 0; r < 4; r++) acc[i][j][r] = 0.f;

    #pragma unroll
    for (int it = 0; it < 4; it++) {
        int y = ay[it] - 1, xx = ax[it] - 1;
        float4 av = make_float4(0.f,0.f,0.f,0.f);
        if ((unsigned)y < 32u && (unsigned)xx < 32u)
            av = *(const float4*)(Xd + ((size_t)(abase[it] + (y<<5) + xx) << 8) + (sseg[it] << 3));
        *(float4*)((char*)As[0] + swb[it]) = av;
        float4 bv = *(const float4*)(Wt + (size_t)(bn + srow[it]) * 2304 + (sseg[it] << 3));
        *(float4*)((char*)Bs[0] + swb[it]) = bv;
    }
    __syncthreads();

    int cur = 0;
    for (int t = 0; t < 18; t++) {
        float4 ra[4], rb[4];
        const bool has_next = (t + 1 < 18);
        if (has_next) {
            int tn = t + 1;
            int tap = tn >> 1;
            int dy = tap / 3 - 1;
            int dx = tap - (tap / 3) * 3 - 1;
            int i0 = (tn & 1) << 7;
            #pragma unroll
            for (int it = 0; it < 4; it++) {
                int y = ay[it] + dy, xx = ax[it] + dx;
                ra[it] = make_float4(0.f,0.f,0.f,0.f);
                if ((unsigned)y < 32u && (unsigned)xx < 32u)
                    ra[it] = *(const float4*)(Xd + ((size_t)(abase[it] + (y<<5) + xx) << 8) + i0 + (sseg[it] << 3));
                rb[it] = *(const float4*)(Wt + (size_t)(bn + srow[it]) * 2304 + tn * 128 + (sseg[it] << 3));
            }
        }
        #pragma unroll
        for (int ks = 0; ks < 4; ks++) {
            bf16x8 af[2], bfr[2];
            #pragma unroll
            for (int i = 0; i < 2; i++)
                af[i] = lds_frag256(As[cur], (wr<<5) + (i<<4) + l16, (ks<<6) + (g<<4));
            #pragma unroll
            for (int j = 0; j < 2; j++)
                bfr[j] = lds_frag256(Bs[cur], (wc<<5) + (j<<4) + l16, (ks<<6) + (g<<4));
            #pragma unroll
            for (int i = 0; i < 2; i++)
                #pragma unroll
                for (int j = 0; j < 2; j++)
                    acc[i][j] = __builtin_amdgcn_mfma_f32_16x16x32_bf16(af[i], bfr[j], acc[i][j], 0, 0, 0);
        }
        if (has_next) {
            #pragma unroll
            for (int it = 0; it < 4; it++) {
                *(float4*)((char*)As[cur^1] + swb[it]) = ra[it];
                *(float4*)((char*)Bs[cur^1] + swb[it]) = rb[it];
            }
        }
        __syncthreads();
        cur ^= 1;
    }

    const float bn_s = 0.99999500003749968f;
    #pragma unroll
    for (int i = 0; i < 2; i++) {
        int m = bm + (wr<<5) + (i<<4) + (g<<2);
        #pragma unroll
        for (int j = 0; j < 2; j++) {
            int c = bn + (wc<<5) + (j<<4) + l16;
            float sc = bn_g[c] * bn_s, bb = bn_b[c], bi = bias[c];
            #pragma unroll
            for (int r = 0; r < 4; r++)
                C[(size_t)(m + r) * 256 + c] = fmaxf((acc[i][j][r] + bi) * sc + bb, 0.f);
        }
    }
}

// ================= merged prep: cvt + 6 weight transposes + conv filter =============
static __device__ inline void tr_task(const float* in, __hip_bfloat16* o,
                                      int K, int N, int nb, int tid)
{
    int idx = nb * 256 + tid;
    int n = idx / K, k = idx - n * K;
    o[idx] = __float2bfloat16(in[(size_t)k * N + n]);
}

__global__ void prep_all(const float* __restrict__ x,
                         const float* __restrict__ sqkv_w, const float* __restrict__ wq_w,
                         const float* __restrict__ reduce_w, const float* __restrict__ sproj_w,
                         const float* __restrict__ wkv_w, const float* __restrict__ wproj_w,
                         const float* __restrict__ filter_w,
                         __hip_bfloat16* __restrict__ xb, __hip_bfloat16* __restrict__ sqkvT,
                         __hip_bfloat16* __restrict__ wqT, __hip_bfloat16* __restrict__ redT,
                         __hip_bfloat16* __restrict__ sprojT, __hip_bfloat16* __restrict__ wkvT,
                         __hip_bfloat16* __restrict__ wprojT, __hip_bfloat16* __restrict__ wt2b)
{
    int bid = blockIdx.x, tid = threadIdx.x;
    if (bid < 8192) {                       // x -> bf16, 4 elems/thread
        int i = bid * 256 + tid;
        float4 v = ((const float4*)x)[i];
        ushort4 h;
        h.x = f2bf(v.x); h.y = f2bf(v.y); h.z = f2bf(v.z); h.w = f2bf(v.w);
        *(ushort4*)(xb + (size_t)i * 4) = h;
        return;
    }
    bid -= 8192;
    if (bid < 1536) { tr_task(sqkv_w, sqkvT, 512, 768, bid, tid); return; }
    bid -= 1536;
    if (bid < 512)  { tr_task(wq_w, wqT, 512, 256, bid, tid); return; }
    bid -= 512;
    if (bid < 128)  { tr_task(reduce_w, redT, 512, 64, bid, tid); return; }
    bid -= 128;
    if (bid < 256)  { tr_task(sproj_w, sprojT, 256, 256, bid, tid); return; }
    bid -= 256;
    if (bid < 512)  { tr_task(wkv_w, wkvT, 256, 512, bid, tid); return; }
    bid -= 512;
    if (bid < 320)  { tr_task(wproj_w, wprojT, 320, 256, bid, tid); return; }
    bid -= 320;
    {   // conv filter: [o][i][tap] -> [o][tap*256+i]
        int oc = bid;
        const float* src = filter_w + (size_t)(oc * 256 + tid) * 9;
        __hip_bfloat16* dst = wt2b + (size_t)oc * 2304 + tid;
        #pragma unroll
        for (int tap = 0; tap < 9; tap++)
            dst[tap * 256] = __float2bfloat16(src[tap]);
    }
}

// ================= window attention (bf16 in/out) =================
__launch_bounds__(256)
__global__ void win_attn(const __hip_bfloat16* __restrict__ qkv,
                         __hip_bfloat16* __restrict__ sa_o)
{
    int gw = blockIdx.x * 4 + (threadIdx.x >> 6);
    int lane = threadIdx.x & 63;
    int b  = gw >> 12;
    int g  = (gw >> 2) & 1023;
    int sh = gw & 3;
    int hg = g >> 5, wg = g & 31;
    float q[4], k[4], v[4];
    int rows[4];
    #pragma unroll
    for (int l = 0; l < 4; l++) {
        int h = (hg << 1) + (l >> 1), w = (wg << 1) + (l & 1);
        int row = (b << 12) + (h << 6) + w;
        rows[l] = row;
        const __hip_bfloat16* p = qkv + (size_t)row * 768 + sh * 64 + lane;
        q[l] = __bfloat162float(p[0]);
        k[l] = __bfloat162float(p[256]);
        v[l] = __bfloat162float(p[512]);
    }
    float s[4][4];
    #pragma unroll
    for (int l = 0; l < 4; l++)
        #pragma unroll
        for (int m = 0; m < 4; m++) s[l][m] = q[l] * k[m];
    #pragma unroll
    for (int off = 32; off > 0; off >>= 1)
        #pragma unroll
        for (int l = 0; l < 4; l++)
            #pragma unroll
            for (int m = 0; m < 4; m++)
                s[l][m] += __shfl_xor(s[l][m], off, 64);
    #pragma unroll
    for (int l = 0; l < 4; l++) {
        float s0 = s[l][0]*WSCALE, s1 = s[l][1]*WSCALE, s2 = s[l][2]*WSCALE, s3 = s[l][3]*WSCALE;
        float mx = fmaxf(fmaxf(s0,s1), fmaxf(s2,s3));
        float p0 = __expf(s0-mx), p1 = __expf(s1-mx), p2 = __expf(s2-mx), p3 = __expf(s3-mx);
        float inv = 1.f / (p0+p1+p2+p3);
        float o = (p0*v[0] + p1*v[1] + p2*v[2] + p3*v[3]) * inv;
        sa_o[(size_t)rows[l] * 256 + sh * 64 + lane] = __float2bfloat16(o);
    }
}

// ================= Haar DWT (fp32 in -> bf16 channel-last) =================
__global__ void dwt_kernel(const float* __restrict__ r, __hip_bfloat16* __restrict__ xd)
{
    int t = blockIdx.x * 256 + threadIdx.x;
    int o = t & 63;
    int x = (t >> 6) & 31;
    int y = (t >> 11) & 31;
    int b = t >> 16;
    const float* rb = r + (b << 18);
    int base = ((y << 1) << 6) + (x << 1);
    float a  = rb[(base     ) * 64 + o];
    float bb = rb[(base +  1) * 64 + o];
    float c  = rb[(base + 64) * 64 + o];
    float d  = rb[(base + 65) * 64 + o];
    float ll = 0.5f*(a+bb+c+d), lh = 0.5f*(a+bb-c-d);
    float hl = 0.5f*(a-bb+c-d), hh = 0.5f*(a-bb-c+d);
    __hip_bfloat16* outp = xd + (((b << 10) + (y << 5) + x) << 8) + o;
    outp[0]   = __float2bfloat16(ll);
    outp[64]  = __float2bfloat16(lh);
    outp[128] = __float2bfloat16(hl);
    outp[192] = __float2bfloat16(hh);
}

// ================= merged LN (rows 0..4095) + IDWT (blocks 4096..5119) =============
__launch_bounds__(256)
__global__ void ln_idwt(const float* __restrict__ X, const float* __restrict__ g,
                        const float* __restrict__ bta, __hip_bfloat16* __restrict__ Y,
                        __hip_bfloat16* __restrict__ xi)
{
    int bid = blockIdx.x;
    int t = threadIdx.x;
    if (bid < 4096) {
        int row = bid;
        float x = X[(size_t)row * 256 + t];
        __shared__ float red[4];
        int wv = t >> 6, ln = t & 63;
        float s = x;
        #pragma unroll
        for (int off = 32; off > 0; off >>= 1) s += __shfl_xor(s, off, 64);
        if (ln == 0) red[wv] = s;
        __syncthreads();
        float m = (red[0]+red[1]+red[2]+red[3]) * (1.f/256.f);
        float d = x - m;
        float s2 = d * d;
        #pragma unroll
        for (int off = 32; off > 0; off >>= 1) s2 += __shfl_xor(s2, off, 64);
        __syncthreads();
        if (ln == 0) red[wv] = s2;
        __syncthreads();
        float var = (red[0]+red[1]+red[2]+red[3]) * (1.f/256.f);
        float inv = 1.f / sqrtf(var + WEPS);
        Y[(size_t)row * 256 + t] = __float2bfloat16(d * inv * g[t] + bta[t]);
        return;
    }
    int tt = (bid - 4096) * 256 + t;
    int o = tt & 63;
    int x = (tt >> 6) & 31;
    int y = (tt >> 11) & 31;
    int b = tt >> 16;
    const float* p = X + (((b << 10) + (y << 5) + x) << 8);
    float ll = p[o], lh = p[64+o], hl = p[128+o], hh = p[192+o];
    float y00 = 0.5f*(ll+lh+hl+hh);
    float y01 = 0.5f*(ll+lh-hl-hh);
    float y10 = 0.5f*(ll-lh+hl-hh);
    float y11 = 0.5f*(ll-lh-hl+hh);
    __hip_bfloat16* ob = xi + ((size_t)b << 18);
    int base = ((y << 1) << 6) + (x << 1);
    ob[(size_t)(base     ) * 64 + o] = __float2bfloat16(y00);
    ob[(size_t)(base +  1) * 64 + o] = __float2bfloat16(y01);
    ob[(size_t)(base + 64) * 64 + o] = __float2bfloat16(y10);
    ob[(size_t)(base + 65) * 64 + o] = __float2bfloat16(y11);
}

// ================= MFMA flash attention: KVBLK=64, native exp2, cvt_pk ==============
__launch_bounds__(256)
__global__ void flash_mfma(const __hip_bfloat16* __restrict__ qb,
                           const __hip_bfloat16* __restrict__ kb,
                           const __hip_bfloat16* __restrict__ vt,
                           __hip_bfloat16* __restrict__ ow)
{
    __shared__ unsigned short Ks[4096];
    __shared__ unsigned short Vs[4096];
    const int tid = threadIdx.x;
    const int wv = tid >> 6;
    const int lane = tid & 63;
    const int g = lane >> 4, q16 = lane & 15;
    const int bh = blockIdx.y;
    const int b = bh >> 2, wh = bh & 3;
    const int qbase = (blockIdx.x << 6) + (wv << 4);

    const __hip_bfloat16* qp = qb + ((size_t)((b << 12) + qbase + q16)) * 256 + wh * 64 + g * 8;
    bf16x8 qf0 = *(const bf16x8*)qp;
    bf16x8 qf1 = *(const bf16x8*)(qp + 32);

    const __hip_bfloat16* kbase = kb + ((size_t)bh << 16);
    const __hip_bfloat16* vbase = vt + ((size_t)bh << 16);

    f32x4 oacc[4];
    #pragma unroll
    for (int dc = 0; dc < 4; dc++)
        #pragma unroll
        for (int r = 0; r < 4; r++) oacc[dc][r] = 0.f;
    float m_cur = -1e30f;
    float lsum_part = 0.f;

    for (int t0 = 0; t0 < 1024; t0 += 64) {
        __syncthreads();
        #pragma unroll
        for (int it = 0; it < 2; it++) {
            int off = (tid << 4) + (it << 12);
            int row = off >> 7;
            int inner = off & 127;
            int wb = row * 128 + (inner ^ ((row & 7) << 4));
            float4 kd = *(const float4*)(kbase + (t0 + row) * 64 + (inner >> 1));
            float4 vd = *(const float4*)(vbase + row * 1024 + t0 + (inner >> 1));
            *(float4*)((char*)Ks + wb) = kd;
            *(float4*)((char*)Vs + wb) = vd;
        }
        __syncthreads();

        f32x4 st[4];
        __builtin_amdgcn_s_setprio(1);
        #pragma unroll
        for (int sub = 0; sub < 4; sub++) {
            #pragma unroll
            for (int r = 0; r < 4; r++) st[sub][r] = 0.f;
            bf16x8 k0 = lds_frag(Ks, sub * 16 + q16, g * 16);
            bf16x8 k1 = lds_frag(Ks, sub * 16 + q16, 64 + g * 16);
            st[sub] = __builtin_amdgcn_mfma_f32_16x16x32_bf16(k0, qf0, st[sub], 0, 0, 0);
            st[sub] = __builtin_amdgcn_mfma_f32_16x16x32_bf16(k1, qf1, st[sub], 0, 0, 0);
        }
        __builtin_amdgcn_s_setprio(0);

        float pmax = -1e30f;
        #pragma unroll
        for (int t = 0; t < 4; t++)
            #pragma unroll
            for (int r = 0; r < 4; r++) pmax = fmaxf(pmax, st[t][r]);
        if (!__all(pmax <= m_cur + 11.5f)) {
            float mx = pmax;
            mx = fmaxf(mx, __shfl_xor(mx, 16, 64));
            mx = fmaxf(mx, __shfl_xor(mx, 32, 64));
            float m_new = fmaxf(m_cur, mx);
            float alpha = exp2_fast(m_cur - m_new);
            lsum_part *= alpha;
            #pragma unroll
            for (int r = 0; r < 4; r++) {
                float sc = __shfl(alpha, (g << 2) + r, 64);
                #pragma unroll
                for (int dc = 0; dc < 4; dc++) oacc[dc][r] *= sc;
            }
            m_cur = m_new;
        }

        float psum = 0.f;
        unsigned pk[4][2];
        #pragma unroll
        for (int t = 0; t < 4; t++) {
            float p0 = exp2_fast(st[t][0] - m_cur), p1 = exp2_fast(st[t][1] - m_cur);
            float p2 = exp2_fast(st[t][2] - m_cur), p3 = exp2_fast(st[t][3] - m_cur);
            psum += (p0 + p1) + (p2 + p3);
            pk[t][0] = cvt_pk_bf16(p0, p1);
            pk[t][1] = cvt_pk_bf16(p2, p3);
        }
        lsum_part += psum;

        bool ghi = (g & 2) != 0;
        unsigned pkA0[2], pkA1[2];
        pkA0[0] = ghi ? pk[1][0] : pk[0][0];
        pkA0[1] = ghi ? pk[1][1] : pk[0][1];
        pkA1[0] = ghi ? pk[3][0] : pk[2][0];
        pkA1[1] = ghi ? pk[3][1] : pk[2][1];
        union { int u[4]; bf16x8 v; } A0, A1;
        #pragma unroll
        for (int c = 0; c < 4; c++) {
            int src = (((2 * g + (c >> 1)) & 3) << 4) | q16;
            A0.u[c] = __shfl((int)pkA0[c & 1], src, 64);
            A1.u[c] = __shfl((int)pkA1[c & 1], src, 64);
        }

        __builtin_amdgcn_s_setprio(1);
        #pragma unroll
        for (int dc = 0; dc < 4; dc++) {
            bf16x8 v0 = lds_frag(Vs, dc * 16 + q16, g * 16);
            bf16x8 v1 = lds_frag(Vs, dc * 16 + q16, 64 + g * 16);
            oacc[dc] = __builtin_amdgcn_mfma_f32_16x16x32_bf16(A0.v, v0, oacc[dc], 0, 0, 0);
            oacc[dc] = __builtin_amdgcn_mfma_f32_16x16x32_bf16(A1.v, v1, oacc[dc], 0, 0, 0);
        }
        __builtin_amdgcn_s_setprio(0);
    }

    lsum_part += __shfl_xor(lsum_part, 16, 64);
    lsum_part += __shfl_xor(lsum_part, 32, 64);
    #pragma unroll
    for (int r = 0; r < 4; r++) {
        float inv = 1.f / __shfl(lsum_part, (g << 2) + r, 64);
        int qrow = (b << 12) + qbase + (g << 2) + r;
        #pragma unroll
        for (int dc = 0; dc < 4; dc++)
            ow[(size_t)qrow * 256 + wh * 64 + dc * 16 + q16] =
                __float2bfloat16(oacc[dc][r] * inv);
    }
}

extern "C" void kernel_launch(void* const* d_in, const int* in_sizes, int n_in,
                              void* d_out, int out_size, void* d_ws, size_t ws_size,
                              hipStream_t stream)
{
    const float* x        = (const float*)d_in[0];
    const float* wq_w     = (const float*)d_in[1];
    const float* kv_ln_g  = (const float*)d_in[2];
    const float* kv_ln_b  = (const float*)d_in[3];
    const float* wkv_w    = (const float*)d_in[4];
    const float* wkv_b    = (const float*)d_in[5];
    const float* wproj_w  = (const float*)d_in[6];
    const float* wproj_b  = (const float*)d_in[7];
    const float* reduce_w = (const float*)d_in[8];
    const float* reduce_b = (const float*)d_in[9];
    const float* rbn_g    = (const float*)d_in[10];
    const float* rbn_b    = (const float*)d_in[11];
    const float* filter_w = (const float*)d_in[12];
    const float* filter_b = (const float*)d_in[13];
    const float* fbn_g    = (const float*)d_in[14];
    const float* fbn_b    = (const float*)d_in[15];
    const float* sqkv_w   = (const float*)d_in[16];
    const float* sproj_w  = (const float*)d_in[17];
    const float* sproj_b  = (const float*)d_in[18];
    float* out = (float*)d_out;
    float* ws  = (float*)d_ws;

    // workspace layout (float units). sqkvT|wqT|redT contiguous = BtAll[1088][512].
    __hip_bfloat16* qkvb  = (__hip_bfloat16*)(ws);             // 12,582,912 bf16
    __hip_bfloat16* owb   = (__hip_bfloat16*)(ws);             // reuse after win_attn
    __hip_bfloat16* sa_ob = (__hip_bfloat16*)(ws + 6291456);   // 4,194,304 bf16
    __hip_bfloat16* xb    = (__hip_bfloat16*)(ws + 8388608);   // 8,388,608 bf16
    __hip_bfloat16* sqkvT = (__hip_bfloat16*)(ws + 12582912);  // 393,216 bf16
    __hip_bfloat16* wqT   = (__hip_bfloat16*)(ws + 12779520);  // 131,072 bf16
    __hip_bfloat16* redT  = (__hip_bfloat16*)(ws + 12845056);  // 32,768 bf16
    __hip_bfloat16* sprojT= (__hip_bfloat16*)(ws + 12861440);  // 65,536 bf16
    __hip_bfloat16* wkvT  = (__hip_bfloat16*)(ws + 12894208);  // 131,072 bf16
    __hip_bfloat16* wprojT= (__hip_bfloat16*)(ws + 13025280);  // 81,920 bf16
    __hip_bfloat16* wt2b  = (__hip_bfloat16*)(ws + 13066240);  // 589,824 bf16
    float* rbuf  = ws + 13361152;                              // 1,048,576 f
    __hip_bfloat16* xd1b  = (__hip_bfloat16*)(ws + 14409728);  // 1,048,576 bf16
    float* xd2   = ws + 14934016;                              // 1,048,576 f
    __hip_bfloat16* kvinb = (__hip_bfloat16*)(ws + 15982592);  // 1,048,576 bf16
    __hip_bfloat16* xidwtb= (__hip_bfloat16*)(ws + 16506880);  // 1,048,576 bf16
    __hip_bfloat16* qbw   = (__hip_bfloat16*)(ws + 17031168);  // 4,194,304 bf16
    __hip_bfloat16* kbb   = (__hip_bfloat16*)(ws + 19128320);  // 1,048,576 bf16
    __hip_bfloat16* vtb   = (__hip_bfloat16*)(ws + 19652608);  // 1,048,576 bf16

    dim3 blk(256);

    // prep: single merged launch
    prep_all<<<dim3(11712), blk, 0, stream>>>(x, sqkv_w, wq_w, reduce_w, sproj_w,
                                              wkv_w, wproj_w, filter_w,
                                              xb, sqkvT, wqT, redT, sprojT, wkvT,
                                              wprojT, wt2b);

    // 1. fused head GEMM (dbuf + XCD swizzle, 1152 blocks)
    gemmX<<<dim3(1152), blk, 0, stream>>>(xb, sqkvT, qkvb, qbw, rbuf,
                                          reduce_b, rbn_g, rbn_b);
    // 2. window attention
    win_attn<<<dim3(4096), blk, 0, stream>>>(qkvb, sa_ob);
    // 3. sa_out -> out cols [0,256)  (dbuf + XCD swizzle, nbx=2, 256 blocks)
    gemm_bf16<EPI_BIAS,0><<<dim3(256), blk, 0, stream>>>(sa_ob, 256, sprojT, 256, out, 512,
                                                         256, 2, sproj_b, nullptr, nullptr, 1.f);
    // 4. DWT -> bf16
    dwt_kernel<<<dim3(1024), blk, 0, stream>>>(rbuf, xd1b);
    // 5. 3x3 conv MFMA + BN + ReLU -> fp32 xd2
    conv3_mfma<<<dim3(4,64), blk, 0, stream>>>(xd1b, wt2b, xd2, filter_b, fbn_g, fbn_b);
    // 6. layernorm + IDWT (merged)
    ln_idwt<<<dim3(5120), blk, 0, stream>>>(xd2, kv_ln_g, kv_ln_b, kvinb, xidwtb);
    // 7. kv GEMM -> bf16 K + transposed V
    gemm64_kv<<<dim3(8,64), blk, 0, stream>>>(kvinb, wkvT, kbb, vtb, wkv_b);
    // 8. flash attention -> bf16 ow
    flash_mfma<<<dim3(64,16), blk, 0, stream>>>(qbw, kbb, vtb, owb);
    // 9. fused wproj -> out cols [256,512)  (dbuf + XCD swizzle, 256 blocks)
    gemm_wproj<<<dim3(256), blk, 0, stream>>>(owb, xidwtb, wprojT, out + 256, wproj_b);
}

// Round 12
// 159.202 us; speedup vs baseline: 1.3021x; 1.3021x over previous
//
#include <hip/hip_runtime.h>
#include <hip/hip_bf16.h>
#include <math.h>

#define WEPS 1e-5f
#define WSCALE 0.125f
#define QSCALE 0.1803368801111244f   // 0.125 * log2(e)

enum { EPI_NONE=0, EPI_BIAS=1, EPI_BN_RELU=2 };

typedef __attribute__((ext_vector_type(8))) short bf16x8;
typedef __attribute__((ext_vector_type(4))) float f32x4;

static __device__ inline unsigned short f2bf(float f) {
    __hip_bfloat16 h = __float2bfloat16(f);
    return *(unsigned short*)&h;
}
// native 2^x (v_exp_f32 computes exp2)
static __device__ inline float exp2_fast(float x) {
    float r;
    asm("v_exp_f32 %0, %1" : "=v"(r) : "v"(x));
    return r;
}
// packed f32x2 -> bf16x2 (lo = a, hi = b)
static __device__ inline unsigned cvt_pk_bf16(float a, float b) {
    unsigned r;
    asm("v_cvt_pk_bf16_f32 %0, %1, %2" : "=v"(r) : "v"(a), "v"(b));
    return r;
}
// XCD-aware chunked swizzle (gridDim.x % 8 == 0)
static __device__ inline int xcd_swizzle_id() {
    int id = blockIdx.x;
    int q = gridDim.x >> 3;
    return (id & 7) * q + (id >> 3);
}

// swizzled LDS 16B fragment read: 128B rows, byte ^= (row&7)<<4
static __device__ inline bf16x8 lds_frag(const unsigned short* base, int row, int inner) {
    int byte = row * 128 + (inner ^ ((row & 7) << 4));
    return *(const bf16x8*)((const char*)base + byte);
}
// swizzled LDS 16B fragment read: 256B rows, byte ^= (row&15)<<4
static __device__ inline bf16x8 lds_frag256(const unsigned short* base, int row, int inner) {
    int byte = row * 256 + (inner ^ ((row & 15) << 4));
    return *(const bf16x8*)((const char*)base + byte);
}

// ================= bf16 MFMA GEMM, 128x128 tile (2-barrier, XCD swizzle) =============
// ROUND-10 PROVEN VERSION — do NOT dbuf: at 1 block/CU the dbuf schedule regresses
// (r11: 42us, Occ 6.3%). 1D grid = nbx*(M/128); w = swz id; bm = w/nbx, bn = w%nbx.
template<int EPI, int OBF16>
__launch_bounds__(256)
__global__ void gemm_bf16(const __hip_bfloat16* __restrict__ A, int lda,
                          const __hip_bfloat16* __restrict__ Bt, int K,
                          void* __restrict__ Cv, int ldc, int N, int nbx,
                          const float* __restrict__ bias,
                          const float* __restrict__ bn_g,
                          const float* __restrict__ bn_b,
                          float oscale)
{
    __shared__ unsigned short As[8192];
    __shared__ unsigned short Bs[8192];
    const int tid = threadIdx.x;
    const int lane = tid & 63, wv = tid >> 6;
    const int g = lane >> 4, l16 = lane & 15;
    const int wr = wv >> 1, wc = wv & 1;
    const int w = xcd_swizzle_id();
    const int bm = (w / nbx) << 7;
    const int bn = (w % nbx) << 7;
    f32x4 acc[4][4];
    #pragma unroll
    for (int i = 0; i < 4; i++)
        #pragma unroll
        for (int j = 0; j < 4; j++)
            #pragma unroll
            for (int r = 0; r < 4; r++) acc[i][j][r] = 0.f;

    for (int k0 = 0; k0 < K; k0 += 64) {
        __syncthreads();
        #pragma unroll
        for (int it = 0; it < 4; it++) {
            int idx = tid + (it << 8);
            int row = idx >> 3, seg = idx & 7;
            int wb = row * 128 + ((seg << 4) ^ ((row & 7) << 4));
            float4 av = *(const float4*)(A + (size_t)(bm + row) * lda + k0 + (seg << 3));
            *(float4*)((char*)As + wb) = av;
            int col = bn + row;
            float4 bv = make_float4(0.f,0.f,0.f,0.f);
            if (col < N) bv = *(const float4*)(Bt + (size_t)col * K + k0 + (seg << 3));
            *(float4*)((char*)Bs + wb) = bv;
        }
        __syncthreads();
        #pragma unroll
        for (int ks = 0; ks < 2; ks++) {
            bf16x8 af[4], bfr[4];
            #pragma unroll
            for (int i = 0; i < 4; i++)
                af[i] = lds_frag(As, (wr<<6) + (i<<4) + l16, (ks<<6) + (g<<4));
            #pragma unroll
            for (int j = 0; j < 4; j++)
                bfr[j] = lds_frag(Bs, (wc<<6) + (j<<4) + l16, (ks<<6) + (g<<4));
            #pragma unroll
            for (int i = 0; i < 4; i++)
                #pragma unroll
                for (int j = 0; j < 4; j++)
                    acc[i][j] = __builtin_amdgcn_mfma_f32_16x16x32_bf16(af[i], bfr[j], acc[i][j], 0, 0, 0);
        }
    }
    const float bn_s = 0.99999500003749968f;
    #pragma unroll
    for (int i = 0; i < 4; i++) {
        int m = bm + (wr<<6) + (i<<4) + (g<<2);
        #pragma unroll
        for (int j = 0; j < 4; j++) {
            int c = bn + (wc<<6) + (j<<4) + l16;
            if (c >= N) continue;
            float bi = (EPI != EPI_NONE) ? bias[c] : 0.f;
            float sc = 1.f, bb = 0.f;
            if (EPI == EPI_BN_RELU) { sc = bn_g[c] * bn_s; bb = bn_b[c]; }
            #pragma unroll
            for (int r = 0; r < 4; r++) {
                float t = acc[i][j][r] * oscale + bi;
                if (EPI == EPI_BN_RELU) t = fmaxf(t * sc + bb, 0.f);
                if (OBF16) ((__hip_bfloat16*)Cv)[(size_t)(m+r)*ldc + c] = __float2bfloat16(t);
                else       ((float*)Cv)[(size_t)(m+r)*ldc + c] = t;
            }
        }
    }
}

// ================= fused head GEMM: xb @ [sqkv|wq|reduce], dbuf + XCD swizzle =======
// KEEP dbuf: 1152 blocks = 4.5/CU, r11 improved it 58 -> <42us.
__launch_bounds__(256)
__global__ void gemmX(const __hip_bfloat16* __restrict__ A,
                      const __hip_bfloat16* __restrict__ Bt,
                      __hip_bfloat16* __restrict__ qkvb,
                      __hip_bfloat16* __restrict__ qbw,
                      float* __restrict__ rbuf,
                      const float* __restrict__ red_b,
                      const float* __restrict__ rbn_g,
                      const float* __restrict__ rbn_b)
{
    __shared__ unsigned short As[2][8192];
    __shared__ unsigned short Bs[2][8192];
    const int tid = threadIdx.x;
    const int lane = tid & 63, wv = tid >> 6;
    const int g = lane >> 4, l16 = lane & 15;
    const int wr = wv >> 1, wc = wv & 1;
    const int w = xcd_swizzle_id();
    const int bm = (w / 9) << 7;
    const int bn = (w % 9) << 7;

    int swb[4];
    const __hip_bfloat16 *Ap[4], *Bp[4];
    bool bok[4];
    #pragma unroll
    for (int it = 0; it < 4; it++) {
        int idx = tid + (it << 8);
        int row = idx >> 3, seg = idx & 7;
        swb[it] = row * 128 + ((seg << 4) ^ ((row & 7) << 4));
        Ap[it] = A + (size_t)(bm + row) * 512 + (seg << 3);
        int col = bn + row;
        bok[it] = col < 1088;
        Bp[it] = Bt + (size_t)(bok[it] ? col : 0) * 512 + (seg << 3);
    }
    f32x4 acc[4][4];
    #pragma unroll
    for (int i = 0; i < 4; i++)
        #pragma unroll
        for (int j = 0; j < 4; j++)
            #pragma unroll
            for (int r = 0; r < 4; r++) acc[i][j][r] = 0.f;

    #pragma unroll
    for (int it = 0; it < 4; it++) {
        *(float4*)((char*)As[0] + swb[it]) = *(const float4*)(Ap[it]);
        float4 bv = make_float4(0.f,0.f,0.f,0.f);
        if (bok[it]) bv = *(const float4*)(Bp[it]);
        *(float4*)((char*)Bs[0] + swb[it]) = bv;
    }
    __syncthreads();

    int cur = 0;
    for (int t = 0; t < 8; t++) {
        float4 ra[4], rb[4];
        const bool has_next = (t < 7);
        if (has_next) {
            int kb = (t + 1) << 6;
            #pragma unroll
            for (int it = 0; it < 4; it++) {
                ra[it] = *(const float4*)(Ap[it] + kb);
                rb[it] = make_float4(0.f,0.f,0.f,0.f);
                if (bok[it]) rb[it] = *(const float4*)(Bp[it] + kb);
            }
        }
        #pragma unroll
        for (int ks = 0; ks < 2; ks++) {
            bf16x8 af[4], bfr[4];
            #pragma unroll
            for (int i = 0; i < 4; i++)
                af[i] = lds_frag(As[cur], (wr<<6) + (i<<4) + l16, (ks<<6) + (g<<4));
            #pragma unroll
            for (int j = 0; j < 4; j++)
                bfr[j] = lds_frag(Bs[cur], (wc<<6) + (j<<4) + l16, (ks<<6) + (g<<4));
            #pragma unroll
            for (int i = 0; i < 4; i++)
                #pragma unroll
                for (int j = 0; j < 4; j++)
                    acc[i][j] = __builtin_amdgcn_mfma_f32_16x16x32_bf16(af[i], bfr[j], acc[i][j], 0, 0, 0);
        }
        if (has_next) {
            #pragma unroll
            for (int it = 0; it < 4; it++) {
                *(float4*)((char*)As[cur^1] + swb[it]) = ra[it];
                *(float4*)((char*)Bs[cur^1] + swb[it]) = rb[it];
            }
        }
        __syncthreads();
        cur ^= 1;
    }
    const float bn_s = 0.99999500003749968f;
    #pragma unroll
    for (int i = 0; i < 4; i++) {
        int m = bm + (wr<<6) + (i<<4) + (g<<2);
        #pragma unroll
        for (int j = 0; j < 4; j++) {
            int c = bn + (wc<<6) + (j<<4) + l16;
            if (c >= 1088) continue;
            if (c < 768) {
                #pragma unroll
                for (int r = 0; r < 4; r++)
                    qkvb[(size_t)(m+r)*768 + c] = __float2bfloat16(acc[i][j][r]);
            } else if (c < 1024) {
                int c2 = c - 768;
                #pragma unroll
                for (int r = 0; r < 4; r++)
                    qbw[(size_t)(m+r)*256 + c2] = __float2bfloat16(acc[i][j][r] * QSCALE);
            } else {
                int c2 = c - 1024;
                float sc = rbn_g[c2] * bn_s, bb = rbn_b[c2], bi = red_b[c2];
                #pragma unroll
                for (int r = 0; r < 4; r++)
                    rbuf[(size_t)(m+r)*64 + c2] = fmaxf((acc[i][j][r] + bi) * sc + bb, 0.f);
            }
        }
    }
}

// ================= kv GEMM, 64x64 tile dbuf: K row-major + V transposed out =========
__launch_bounds__(256)
__global__ void gemm64_kv(const __hip_bfloat16* __restrict__ A,
                          const __hip_bfloat16* __restrict__ Bt,
                          __hip_bfloat16* __restrict__ kbo,   // [16][1024][64]
                          __hip_bfloat16* __restrict__ vto,   // [16][64][1024]
                          const float* __restrict__ bias)
{
    __shared__ unsigned short As[2][4096];
    __shared__ unsigned short Bs[2][4096];
    const int tid = threadIdx.x;
    const int lane = tid & 63, wv = tid >> 6;
    const int g = lane >> 4, l16 = lane & 15;
    const int wr = wv >> 1, wc = wv & 1;
    const int bm = blockIdx.y << 6;
    const int bn = blockIdx.x << 6;

    int swb[2];
    const __hip_bfloat16 *Ap[2], *Bp[2];
    #pragma unroll
    for (int it = 0; it < 2; it++) {
        int idx = tid + (it << 8);
        int row = idx >> 3, seg = idx & 7;
        swb[it] = row * 128 + ((seg << 4) ^ ((row & 7) << 4));
        Ap[it] = A  + (size_t)(bm + row) * 256 + (seg << 3);
        Bp[it] = Bt + (size_t)(bn + row) * 256 + (seg << 3);
    }
    f32x4 acc[2][2];
    #pragma unroll
    for (int i = 0; i < 2; i++)
        #pragma unroll
        for (int j = 0; j < 2; j++)
            #pragma unroll
            for (int r = 0; r < 4; r++) acc[i][j][r] = 0.f;

    #pragma unroll
    for (int it = 0; it < 2; it++) {
        *(float4*)((char*)As[0] + swb[it]) = *(const float4*)(Ap[it]);
        *(float4*)((char*)Bs[0] + swb[it]) = *(const float4*)(Bp[it]);
    }
    __syncthreads();

    int cur = 0;
    for (int t = 0; t < 4; t++) {
        float4 ra[2], rb[2];
        const bool has_next = (t < 3);
        if (has_next) {
            #pragma unroll
            for (int it = 0; it < 2; it++) {
                ra[it] = *(const float4*)(Ap[it] + ((t + 1) << 6));
                rb[it] = *(const float4*)(Bp[it] + ((t + 1) << 6));
            }
        }
        #pragma unroll
        for (int ks = 0; ks < 2; ks++) {
            bf16x8 af[2], bfr[2];
            #pragma unroll
            for (int i = 0; i < 2; i++)
                af[i] = lds_frag(As[cur], (wr<<5) + (i<<4) + l16, (ks<<6) + (g<<4));
            #pragma unroll
            for (int j = 0; j < 2; j++)
                bfr[j] = lds_frag(Bs[cur], (wc<<5) + (j<<4) + l16, (ks<<6) + (g<<4));
            #pragma unroll
            for (int i = 0; i < 2; i++)
                #pragma unroll
                for (int j = 0; j < 2; j++)
                    acc[i][j] = __builtin_amdgcn_mfma_f32_16x16x32_bf16(af[i], bfr[j], acc[i][j], 0, 0, 0);
        }
        if (has_next) {
            #pragma unroll
            for (int it = 0; it < 2; it++) {
                *(float4*)((char*)As[cur^1] + swb[it]) = ra[it];
                *(float4*)((char*)Bs[cur^1] + swb[it]) = rb[it];
            }
        }
        __syncthreads();
        cur ^= 1;
    }

    #pragma unroll
    for (int i = 0; i < 2; i++) {
        int m = bm + (wr<<5) + (i<<4) + (g<<2);
        int bimg = m >> 10, tkn0 = m & 1023;
        #pragma unroll
        for (int j = 0; j < 2; j++) {
            int c = bn + (wc<<5) + (j<<4) + l16;
            if (c < 256) {          // K: [bh][token][d]
                int wh = c >> 6, d0 = c & 63;
                __hip_bfloat16* kp = kbo + (((size_t)((bimg<<2)+wh)) << 16) + (size_t)tkn0*64 + d0;
                #pragma unroll
                for (int r = 0; r < 4; r++)
                    kp[r*64] = __float2bfloat16(acc[i][j][r] + bias[c]);
            } else {                // V: [bh][d][token]
                int c2 = c - 256;
                int wh = c2 >> 6, d = c2 & 63;
                float bi = bias[256 + c2];
                ushort4 h;
                h.x = f2bf(acc[i][j][0] + bi);
                h.y = f2bf(acc[i][j][1] + bi);
                h.z = f2bf(acc[i][j][2] + bi);
                h.w = f2bf(acc[i][j][3] + bi);
                *(ushort4*)(vto + (((size_t)((bimg<<2)+wh)) << 16) + (size_t)d*1024 + tkn0) = h;
            }
        }
    }
}

// ================= fused wproj GEMM, 128x128 2-barrier + XCD swizzle ================
// ROUND-10 PROVEN VERSION (1 block/CU: keep 2-barrier). Grid 256 (1D).
__launch_bounds__(256)
__global__ void gemm_wproj(const __hip_bfloat16* __restrict__ A1,
                           const __hip_bfloat16* __restrict__ A2,
                           const __hip_bfloat16* __restrict__ Bt,  // [256][320]
                           float* __restrict__ C,                  // out+256, ldc=512
                           const float* __restrict__ bias)
{
    __shared__ unsigned short As[8192];
    __shared__ unsigned short Bs[8192];
    const int tid = threadIdx.x;
    const int lane = tid & 63, wv = tid >> 6;
    const int g = lane >> 4, l16 = lane & 15;
    const int wr = wv >> 1, wc = wv & 1;
    const int w = xcd_swizzle_id();
    const int bm = (w >> 1) << 7;
    const int bn = (w & 1) << 7;
    f32x4 acc[4][4];
    #pragma unroll
    for (int i = 0; i < 4; i++)
        #pragma unroll
        for (int j = 0; j < 4; j++)
            #pragma unroll
            for (int r = 0; r < 4; r++) acc[i][j][r] = 0.f;

    for (int k0 = 0; k0 < 320; k0 += 64) {
        __syncthreads();
        #pragma unroll
        for (int it = 0; it < 4; it++) {
            int idx = tid + (it << 8);
            int row = idx >> 3, seg = idx & 7;
            int wb = row * 128 + ((seg << 4) ^ ((row & 7) << 4));
            float4 av;
            if (k0 < 256)
                av = *(const float4*)(A1 + (size_t)(bm + row) * 256 + k0 + (seg << 3));
            else
                av = *(const float4*)(A2 + (size_t)(bm + row) * 64 + (k0 - 256) + (seg << 3));
            *(float4*)((char*)As + wb) = av;
            float4 bv = *(const float4*)(Bt + (size_t)(bn + row) * 320 + k0 + (seg << 3));
            *(float4*)((char*)Bs + wb) = bv;
        }
        __syncthreads();
        #pragma unroll
        for (int ks = 0; ks < 2; ks++) {
            bf16x8 af[4], bfr[4];
            #pragma unroll
            for (int i = 0; i < 4; i++)
                af[i] = lds_frag(As, (wr<<6) + (i<<4) + l16, (ks<<6) + (g<<4));
            #pragma unroll
            for (int j = 0; j < 4; j++)
                bfr[j] = lds_frag(Bs, (wc<<6) + (j<<4) + l16, (ks<<6) + (g<<4));
            #pragma unroll
            for (int i = 0; i < 4; i++)
                #pragma unroll
                for (int j = 0; j < 4; j++)
                    acc[i][j] = __builtin_amdgcn_mfma_f32_16x16x32_bf16(af[i], bfr[j], acc[i][j], 0, 0, 0);
        }
    }
    #pragma unroll
    for (int i = 0; i < 4; i++) {
        int m = bm + (wr<<6) + (i<<4) + (g<<2);
        #pragma unroll
        for (int j = 0; j < 4; j++) {
            int c = bn + (wc<<6) + (j<<4) + l16;
            float bi = bias[c];
            #pragma unroll
            for (int r = 0; r < 4; r++)
                C[(size_t)(m+r)*512 + c] = acc[i][j][r] + bi;
        }
    }
}

// ================= 3x3 conv: bf16 MFMA, 64x64 tile, BK=128, double-buffered =====
__launch_bounds__(256)
__global__ void conv3_mfma(const __hip_bfloat16* __restrict__ Xd,
                           const __hip_bfloat16* __restrict__ Wt,
                           float* __restrict__ C,
                           const float* __restrict__ bias,
                           const float* __restrict__ bn_g,
                           const float* __restrict__ bn_b)
{
    __shared__ unsigned short As[2][8192];
    __shared__ unsigned short Bs[2][8192];
    const int tid = threadIdx.x;
    const int lane = tid & 63, wv = tid >> 6;
    const int g = lane >> 4, l16 = lane & 15;
    const int wr = wv >> 1, wc = wv & 1;
    const int bm = blockIdx.y << 6;
    const int bn = blockIdx.x << 6;

    int srow[4], sseg[4], swb[4];
    #pragma unroll
    for (int it = 0; it < 4; it++) {
        int idx = tid + (it << 8);
        srow[it] = idx >> 4;
        sseg[it] = idx & 15;
        swb[it]  = srow[it] * 256 + ((sseg[it] << 4) ^ ((srow[it] & 15) << 4));
    }
    int abase[4], ay[4], ax[4];
    #pragma unroll
    for (int it = 0; it < 4; it++) {
        int m = bm + srow[it];
        int bimg = m >> 10, s = m & 1023;
        ay[it] = s >> 5; ax[it] = s & 31;
        abase[it] = bimg << 10;
    }

    f32x4 acc[2][2];
    #pragma unroll
    for (int i = 0; i < 2; i++)
        #pragma unroll
        for (int j = 0; j < 2; j++)
            #pragma unroll
            for (int r = 0; r < 4; r++) acc[i][j][r] = 0.f;

    #pragma unroll
    for (int it = 0; it < 4; it++) {
        int y = ay[it] - 1, xx = ax[it] - 1;
        float4 av = make_float4(0.f,0.f,0.f,0.f);
        if ((unsigned)y < 32u && (unsigned)xx < 32u)
            av = *(const float4*)(Xd + ((size_t)(abase[it] + (y<<5) + xx) << 8) + (sseg[it] << 3));
        *(float4*)((char*)As[0] + swb[it]) = av;
        float4 bv = *(const float4*)(Wt + (size_t)(bn + srow[it]) * 2304 + (sseg[it] << 3));
        *(float4*)((char*)Bs[0] + swb[it]) = bv;
    }
    __syncthreads();

    int cur = 0;
    for (int t = 0; t < 18; t++) {
        float4 ra[4], rb[4];
        const bool has_next = (t + 1 < 18);
        if (has_next) {
            int tn = t + 1;
            int tap = tn >> 1;
            int dy = tap / 3 - 1;
            int dx = tap - (tap / 3) * 3 - 1;
            int i0 = (tn & 1) << 7;
            #pragma unroll
            for (int it = 0; it < 4; it++) {
                int y = ay[it] + dy, xx = ax[it] + dx;
                ra[it] = make_float4(0.f,0.f,0.f,0.f);
                if ((unsigned)y < 32u && (unsigned)xx < 32u)
                    ra[it] = *(const float4*)(Xd + ((size_t)(abase[it] + (y<<5) + xx) << 8) + i0 + (sseg[it] << 3));
                rb[it] = *(const float4*)(Wt + (size_t)(bn + srow[it]) * 2304 + tn * 128 + (sseg[it] << 3));
            }
        }
        #pragma unroll
        for (int ks = 0; ks < 4; ks++) {
            bf16x8 af[2], bfr[2];
            #pragma unroll
            for (int i = 0; i < 2; i++)
                af[i] = lds_frag256(As[cur], (wr<<5) + (i<<4) + l16, (ks<<6) + (g<<4));
            #pragma unroll
            for (int j = 0; j < 2; j++)
                bfr[j] = lds_frag256(Bs[cur], (wc<<5) + (j<<4) + l16, (ks<<6) + (g<<4));
            #pragma unroll
            for (int i = 0; i < 2; i++)
                #pragma unroll
                for (int j = 0; j < 2; j++)
                    acc[i][j] = __builtin_amdgcn_mfma_f32_16x16x32_bf16(af[i], bfr[j], acc[i][j], 0, 0, 0);
        }
        if (has_next) {
            #pragma unroll
            for (int it = 0; it < 4; it++) {
                *(float4*)((char*)As[cur^1] + swb[it]) = ra[it];
                *(float4*)((char*)Bs[cur^1] + swb[it]) = rb[it];
            }
        }
        __syncthreads();
        cur ^= 1;
    }

    const float bn_s = 0.99999500003749968f;
    #pragma unroll
    for (int i = 0; i < 2; i++) {
        int m = bm + (wr<<5) + (i<<4) + (g<<2);
        #pragma unroll
        for (int j = 0; j < 2; j++) {
            int c = bn + (wc<<5) + (j<<4) + l16;
            float sc = bn_g[c] * bn_s, bb = bn_b[c], bi = bias[c];
            #pragma unroll
            for (int r = 0; r < 4; r++)
                C[(size_t)(m + r) * 256 + c] = fmaxf((acc[i][j][r] + bi) * sc + bb, 0.f);
        }
    }
}

// ================= merged prep: cvt + 6 weight transposes + conv filter =============
static __device__ inline void tr_task(const float* in, __hip_bfloat16* o,
                                      int K, int N, int nb, int tid)
{
    int idx = nb * 256 + tid;
    int n = idx / K, k = idx - n * K;
    o[idx] = __float2bfloat16(in[(size_t)k * N + n]);
}

__global__ void prep_all(const float* __restrict__ x,
                         const float* __restrict__ sqkv_w, const float* __restrict__ wq_w,
                         const float* __restrict__ reduce_w, const float* __restrict__ sproj_w,
                         const float* __restrict__ wkv_w, const float* __restrict__ wproj_w,
                         const float* __restrict__ filter_w,
                         __hip_bfloat16* __restrict__ xb, __hip_bfloat16* __restrict__ sqkvT,
                         __hip_bfloat16* __restrict__ wqT, __hip_bfloat16* __restrict__ redT,
                         __hip_bfloat16* __restrict__ sprojT, __hip_bfloat16* __restrict__ wkvT,
                         __hip_bfloat16* __restrict__ wprojT, __hip_bfloat16* __restrict__ wt2b)
{
    int bid = blockIdx.x, tid = threadIdx.x;
    if (bid < 8192) {                       // x -> bf16, 4 elems/thread
        int i = bid * 256 + tid;
        float4 v = ((const float4*)x)[i];
        ushort4 h;
        h.x = f2bf(v.x); h.y = f2bf(v.y); h.z = f2bf(v.z); h.w = f2bf(v.w);
        *(ushort4*)(xb + (size_t)i * 4) = h;
        return;
    }
    bid -= 8192;
    if (bid < 1536) { tr_task(sqkv_w, sqkvT, 512, 768, bid, tid); return; }
    bid -= 1536;
    if (bid < 512)  { tr_task(wq_w, wqT, 512, 256, bid, tid); return; }
    bid -= 512;
    if (bid < 128)  { tr_task(reduce_w, redT, 512, 64, bid, tid); return; }
    bid -= 128;
    if (bid < 256)  { tr_task(sproj_w, sprojT, 256, 256, bid, tid); return; }
    bid -= 256;
    if (bid < 512)  { tr_task(wkv_w, wkvT, 256, 512, bid, tid); return; }
    bid -= 512;
    if (bid < 320)  { tr_task(wproj_w, wprojT, 320, 256, bid, tid); return; }
    bid -= 320;
    {   // conv filter: [o][i][tap] -> [o][tap*256+i]
        int oc = bid;
        const float* src = filter_w + (size_t)(oc * 256 + tid) * 9;
        __hip_bfloat16* dst = wt2b + (size_t)oc * 2304 + tid;
        #pragma unroll
        for (int tap = 0; tap < 9; tap++)
            dst[tap * 256] = __float2bfloat16(src[tap]);
    }
}

// ================= window attention (bf16 in/out) =================
__launch_bounds__(256)
__global__ void win_attn(const __hip_bfloat16* __restrict__ qkv,
                         __hip_bfloat16* __restrict__ sa_o)
{
    int gw = blockIdx.x * 4 + (threadIdx.x >> 6);
    int lane = threadIdx.x & 63;
    int b  = gw >> 12;
    int g  = (gw >> 2) & 1023;
    int sh = gw & 3;
    int hg = g >> 5, wg = g & 31;
    float q[4], k[4], v[4];
    int rows[4];
    #pragma unroll
    for (int l = 0; l < 4; l++) {
        int h = (hg << 1) + (l >> 1), w = (wg << 1) + (l & 1);
        int row = (b << 12) + (h << 6) + w;
        rows[l] = row;
        const __hip_bfloat16* p = qkv + (size_t)row * 768 + sh * 64 + lane;
        q[l] = __bfloat162float(p[0]);
        k[l] = __bfloat162float(p[256]);
        v[l] = __bfloat162float(p[512]);
    }
    float s[4][4];
    #pragma unroll
    for (int l = 0; l < 4; l++)
        #pragma unroll
        for (int m = 0; m < 4; m++) s[l][m] = q[l] * k[m];
    #pragma unroll
    for (int off = 32; off > 0; off >>= 1)
        #pragma unroll
        for (int l = 0; l < 4; l++)
            #pragma unroll
            for (int m = 0; m < 4; m++)
                s[l][m] += __shfl_xor(s[l][m], off, 64);
    #pragma unroll
    for (int l = 0; l < 4; l++) {
        float s0 = s[l][0]*WSCALE, s1 = s[l][1]*WSCALE, s2 = s[l][2]*WSCALE, s3 = s[l][3]*WSCALE;
        float mx = fmaxf(fmaxf(s0,s1), fmaxf(s2,s3));
        float p0 = __expf(s0-mx), p1 = __expf(s1-mx), p2 = __expf(s2-mx), p3 = __expf(s3-mx);
        float inv = 1.f / (p0+p1+p2+p3);
        float o = (p0*v[0] + p1*v[1] + p2*v[2] + p3*v[3]) * inv;
        sa_o[(size_t)rows[l] * 256 + sh * 64 + lane] = __float2bfloat16(o);
    }
}

// ================= Haar DWT (fp32 in -> bf16 channel-last) =================
__global__ void dwt_kernel(const float* __restrict__ r, __hip_bfloat16* __restrict__ xd)
{
    int t = blockIdx.x * 256 + threadIdx.x;
    int o = t & 63;
    int x = (t >> 6) & 31;
    int y = (t >> 11) & 31;
    int b = t >> 16;
    const float* rb = r + (b << 18);
    int base = ((y << 1) << 6) + (x << 1);
    float a  = rb[(base     ) * 64 + o];
    float bb = rb[(base +  1) * 64 + o];
    float c  = rb[(base + 64) * 64 + o];
    float d  = rb[(base + 65) * 64 + o];
    float ll = 0.5f*(a+bb+c+d), lh = 0.5f*(a+bb-c-d);
    float hl = 0.5f*(a-bb+c-d), hh = 0.5f*(a-bb-c+d);
    __hip_bfloat16* outp = xd + (((b << 10) + (y << 5) + x) << 8) + o;
    outp[0]   = __float2bfloat16(ll);
    outp[64]  = __float2bfloat16(lh);
    outp[128] = __float2bfloat16(hl);
    outp[192] = __float2bfloat16(hh);
}

// ================= merged LN (rows 0..4095) + IDWT (blocks 4096..5119) =============
__launch_bounds__(256)
__global__ void ln_idwt(const float* __restrict__ X, const float* __restrict__ g,
                        const float* __restrict__ bta, __hip_bfloat16* __restrict__ Y,
                        __hip_bfloat16* __restrict__ xi)
{
    int bid = blockIdx.x;
    int t = threadIdx.x;
    if (bid < 4096) {
        int row = bid;
        float x = X[(size_t)row * 256 + t];
        __shared__ float red[4];
        int wv = t >> 6, ln = t & 63;
        float s = x;
        #pragma unroll
        for (int off = 32; off > 0; off >>= 1) s += __shfl_xor(s, off, 64);
        if (ln == 0) red[wv] = s;
        __syncthreads();
        float m = (red[0]+red[1]+red[2]+red[3]) * (1.f/256.f);
        float d = x - m;
        float s2 = d * d;
        #pragma unroll
        for (int off = 32; off > 0; off >>= 1) s2 += __shfl_xor(s2, off, 64);
        __syncthreads();
        if (ln == 0) red[wv] = s2;
        __syncthreads();
        float var = (red[0]+red[1]+red[2]+red[3]) * (1.f/256.f);
        float inv = 1.f / sqrtf(var + WEPS);
        Y[(size_t)row * 256 + t] = __float2bfloat16(d * inv * g[t] + bta[t]);
        return;
    }
    int tt = (bid - 4096) * 256 + t;
    int o = tt & 63;
    int x = (tt >> 6) & 31;
    int y = (tt >> 11) & 31;
    int b = tt >> 16;
    const float* p = X + (((b << 10) + (y << 5) + x) << 8);
    float ll = p[o], lh = p[64+o], hl = p[128+o], hh = p[192+o];
    float y00 = 0.5f*(ll+lh+hl+hh);
    float y01 = 0.5f*(ll+lh-hl-hh);
    float y10 = 0.5f*(ll-lh+hl-hh);
    float y11 = 0.5f*(ll-lh-hl+hh);
    __hip_bfloat16* ob = xi + ((size_t)b << 18);
    int base = ((y << 1) << 6) + (x << 1);
    ob[(size_t)(base     ) * 64 + o] = __float2bfloat16(y00);
    ob[(size_t)(base +  1) * 64 + o] = __float2bfloat16(y01);
    ob[(size_t)(base + 64) * 64 + o] = __float2bfloat16(y10);
    ob[(size_t)(base + 65) * 64 + o] = __float2bfloat16(y11);
}

// ================= MFMA flash attention: KVBLK=64, native exp2, cvt_pk ==============
__launch_bounds__(256)
__global__ void flash_mfma(const __hip_bfloat16* __restrict__ qb,
                           const __hip_bfloat16* __restrict__ kb,
                           const __hip_bfloat16* __restrict__ vt,
                           __hip_bfloat16* __restrict__ ow)
{
    __shared__ unsigned short Ks[4096];
    __shared__ unsigned short Vs[4096];
    const int tid = threadIdx.x;
    const int wv = tid >> 6;
    const int lane = tid & 63;
    const int g = lane >> 4, q16 = lane & 15;
    const int bh = blockIdx.y;
    const int b = bh >> 2, wh = bh & 3;
    const int qbase = (blockIdx.x << 6) + (wv << 4);

    const __hip_bfloat16* qp = qb + ((size_t)((b << 12) + qbase + q16)) * 256 + wh * 64 + g * 8;
    bf16x8 qf0 = *(const bf16x8*)qp;
    bf16x8 qf1 = *(const bf16x8*)(qp + 32);

    const __hip_bfloat16* kbase = kb + ((size_t)bh << 16);
    const __hip_bfloat16* vbase = vt + ((size_t)bh << 16);

    f32x4 oacc[4];
    #pragma unroll
    for (int dc = 0; dc < 4; dc++)
        #pragma unroll
        for (int r = 0; r < 4; r++) oacc[dc][r] = 0.f;
    float m_cur = -1e30f;
    float lsum_part = 0.f;

    for (int t0 = 0; t0 < 1024; t0 += 64) {
        __syncthreads();
        #pragma unroll
        for (int it = 0; it < 2; it++) {
            int off = (tid << 4) + (it << 12);
            int row = off >> 7;
            int inner = off & 127;
            int wb = row * 128 + (inner ^ ((row & 7) << 4));
            float4 kd = *(const float4*)(kbase + (t0 + row) * 64 + (inner >> 1));
            float4 vd = *(const float4*)(vbase + row * 1024 + t0 + (inner >> 1));
            *(float4*)((char*)Ks + wb) = kd;
            *(float4*)((char*)Vs + wb) = vd;
        }
        __syncthreads();

        f32x4 st[4];
        __builtin_amdgcn_s_setprio(1);
        #pragma unroll
        for (int sub = 0; sub < 4; sub++) {
            #pragma unroll
            for (int r = 0; r < 4; r++) st[sub][r] = 0.f;
            bf16x8 k0 = lds_frag(Ks, sub * 16 + q16, g * 16);
            bf16x8 k1 = lds_frag(Ks, sub * 16 + q16, 64 + g * 16);
            st[sub] = __builtin_amdgcn_mfma_f32_16x16x32_bf16(k0, qf0, st[sub], 0, 0, 0);
            st[sub] = __builtin_amdgcn_mfma_f32_16x16x32_bf16(k1, qf1, st[sub], 0, 0, 0);
        }
        __builtin_amdgcn_s_setprio(0);

        float pmax = -1e30f;
        #pragma unroll
        for (int t = 0; t < 4; t++)
            #pragma unroll
            for (int r = 0; r < 4; r++) pmax = fmaxf(pmax, st[t][r]);
        if (!__all(pmax <= m_cur + 11.5f)) {
            float mx = pmax;
            mx = fmaxf(mx, __shfl_xor(mx, 16, 64));
            mx = fmaxf(mx, __shfl_xor(mx, 32, 64));
            float m_new = fmaxf(m_cur, mx);
            float alpha = exp2_fast(m_cur - m_new);
            lsum_part *= alpha;
            #pragma unroll
            for (int r = 0; r < 4; r++) {
                float sc = __shfl(alpha, (g << 2) + r, 64);
                #pragma unroll
                for (int dc = 0; dc < 4; dc++) oacc[dc][r] *= sc;
            }
            m_cur = m_new;
        }

        float psum = 0.f;
        unsigned pk[4][2];
        #pragma unroll
        for (int t = 0; t < 4; t++) {
            float p0 = exp2_fast(st[t][0] - m_cur), p1 = exp2_fast(st[t][1] - m_cur);
            float p2 = exp2_fast(st[t][2] - m_cur), p3 = exp2_fast(st[t][3] - m_cur);
            psum += (p0 + p1) + (p2 + p3);
            pk[t][0] = cvt_pk_bf16(p0, p1);
            pk[t][1] = cvt_pk_bf16(p2, p3);
        }
        lsum_part += psum;

        bool ghi = (g & 2) != 0;
        unsigned pkA0[2], pkA1[2];
        pkA0[0] = ghi ? pk[1][0] : pk[0][0];
        pkA0[1] = ghi ? pk[1][1] : pk[0][1];
        pkA1[0] = ghi ? pk[3][0] : pk[2][0];
        pkA1[1] = ghi ? pk[3][1] : pk[2][1];
        union { int u[4]; bf16x8 v; } A0, A1;
        #pragma unroll
        for (int c = 0; c < 4; c++) {
            int src = (((2 * g + (c >> 1)) & 3) << 4) | q16;
            A0.u[c] = __shfl((int)pkA0[c & 1], src, 64);
            A1.u[c] = __shfl((int)pkA1[c & 1], src, 64);
        }

        __builtin_amdgcn_s_setprio(1);
        #pragma unroll
        for (int dc = 0; dc < 4; dc++) {
            bf16x8 v0 = lds_frag(Vs, dc * 16 + q16, g * 16);
            bf16x8 v1 = lds_frag(Vs, dc * 16 + q16, 64 + g * 16);
            oacc[dc] = __builtin_amdgcn_mfma_f32_16x16x32_bf16(A0.v, v0, oacc[dc], 0, 0, 0);
            oacc[dc] = __builtin_amdgcn_mfma_f32_16x16x32_bf16(A1.v, v1, oacc[dc], 0, 0, 0);
        }
        __builtin_amdgcn_s_setprio(0);
    }

    lsum_part += __shfl_xor(lsum_part, 16, 64);
    lsum_part += __shfl_xor(lsum_part, 32, 64);
    #pragma unroll
    for (int r = 0; r < 4; r++) {
        float inv = 1.f / __shfl(lsum_part, (g << 2) + r, 64);
        int qrow = (b << 12) + qbase + (g << 2) + r;
        #pragma unroll
        for (int dc = 0; dc < 4; dc++)
            ow[(size_t)qrow * 256 + wh * 64 + dc * 16 + q16] =
                __float2bfloat16(oacc[dc][r] * inv);
    }
}

extern "C" void kernel_launch(void* const* d_in, const int* in_sizes, int n_in,
                              void* d_out, int out_size, void* d_ws, size_t ws_size,
                              hipStream_t stream)
{
    const float* x        = (const float*)d_in[0];
    const float* wq_w     = (const float*)d_in[1];
    const float* kv_ln_g  = (const float*)d_in[2];
    const float* kv_ln_b  = (const float*)d_in[3];
    const float* wkv_w    = (const float*)d_in[4];
    const float* wkv_b    = (const float*)d_in[5];
    const float* wproj_w  = (const float*)d_in[6];
    const float* wproj_b  = (const float*)d_in[7];
    const float* reduce_w = (const float*)d_in[8];
    const float* reduce_b = (const float*)d_in[9];
    const float* rbn_g    = (const float*)d_in[10];
    const float* rbn_b    = (const float*)d_in[11];
    const float* filter_w = (const float*)d_in[12];
    const float* filter_b = (const float*)d_in[13];
    const float* fbn_g    = (const float*)d_in[14];
    const float* fbn_b    = (const float*)d_in[15];
    const float* sqkv_w   = (const float*)d_in[16];
    const float* sproj_w  = (const float*)d_in[17];
    const float* sproj_b  = (const float*)d_in[18];
    float* out = (float*)d_out;
    float* ws  = (float*)d_ws;

    // workspace layout (float units). sqkvT|wqT|redT contiguous = BtAll[1088][512].
    __hip_bfloat16* qkvb  = (__hip_bfloat16*)(ws);             // 12,582,912 bf16
    __hip_bfloat16* owb   = (__hip_bfloat16*)(ws);             // reuse after win_attn
    __hip_bfloat16* sa_ob = (__hip_bfloat16*)(ws + 6291456);   // 4,194,304 bf16
    __hip_bfloat16* xb    = (__hip_bfloat16*)(ws + 8388608);   // 8,388,608 bf16
    __hip_bfloat16* sqkvT = (__hip_bfloat16*)(ws + 12582912);  // 393,216 bf16
    __hip_bfloat16* wqT   = (__hip_bfloat16*)(ws + 12779520);  // 131,072 bf16
    __hip_bfloat16* redT  = (__hip_bfloat16*)(ws + 12845056);  // 32,768 bf16
    __hip_bfloat16* sprojT= (__hip_bfloat16*)(ws + 12861440);  // 65,536 bf16
    __hip_bfloat16* wkvT  = (__hip_bfloat16*)(ws + 12894208);  // 131,072 bf16
    __hip_bfloat16* wprojT= (__hip_bfloat16*)(ws + 13025280);  // 81,920 bf16
    __hip_bfloat16* wt2b  = (__hip_bfloat16*)(ws + 13066240);  // 589,824 bf16
    float* rbuf  = ws + 13361152;                              // 1,048,576 f
    __hip_bfloat16* xd1b  = (__hip_bfloat16*)(ws + 14409728);  // 1,048,576 bf16
    float* xd2   = ws + 14934016;                              // 1,048,576 f
    __hip_bfloat16* kvinb = (__hip_bfloat16*)(ws + 15982592);  // 1,048,576 bf16
    __hip_bfloat16* xidwtb= (__hip_bfloat16*)(ws + 16506880);  // 1,048,576 bf16
    __hip_bfloat16* qbw   = (__hip_bfloat16*)(ws + 17031168);  // 4,194,304 bf16
    __hip_bfloat16* kbb   = (__hip_bfloat16*)(ws + 19128320);  // 1,048,576 bf16
    __hip_bfloat16* vtb   = (__hip_bfloat16*)(ws + 19652608);  // 1,048,576 bf16

    dim3 blk(256);

    // prep: single merged launch
    prep_all<<<dim3(11712), blk, 0, stream>>>(x, sqkv_w, wq_w, reduce_w, sproj_w,
                                              wkv_w, wproj_w, filter_w,
                                              xb, sqkvT, wqT, redT, sprojT, wkvT,
                                              wprojT, wt2b);

    // 1. fused head GEMM (dbuf + XCD swizzle, 1152 blocks = 4.5/CU)
    gemmX<<<dim3(1152), blk, 0, stream>>>(xb, sqkvT, qkvb, qbw, rbuf,
                                          reduce_b, rbn_g, rbn_b);
    // 2. window attention
    win_attn<<<dim3(4096), blk, 0, stream>>>(qkvb, sa_ob);
    // 3. sa_out -> out cols [0,256)  (2-barrier + XCD swizzle, round-10 version)
    gemm_bf16<EPI_BIAS,0><<<dim3(256), blk, 0, stream>>>(sa_ob, 256, sprojT, 256, out, 512,
                                                         256, 2, sproj_b, nullptr, nullptr, 1.f);
    // 4. DWT -> bf16
    dwt_kernel<<<dim3(1024), blk, 0, stream>>>(rbuf, xd1b);
    // 5. 3x3 conv MFMA + BN + ReLU -> fp32 xd2
    conv3_mfma<<<dim3(4,64), blk, 0, stream>>>(xd1b, wt2b, xd2, filter_b, fbn_g, fbn_b);
    // 6. layernorm + IDWT (merged)
    ln_idwt<<<dim3(5120), blk, 0, stream>>>(xd2, kv_ln_g, kv_ln_b, kvinb, xidwtb);
    // 7. kv GEMM -> bf16 K + transposed V
    gemm64_kv<<<dim3(8,64), blk, 0, stream>>>(kvinb, wkvT, kbb, vtb, wkv_b);
    // 8. flash attention -> bf16 ow
    flash_mfma<<<dim3(64,16), blk, 0, stream>>>(qbw, kbb, vtb, owb);
    // 9. fused wproj -> out cols [256,512)  (2-barrier + XCD swizzle, round-10 version)
    gemm_wproj<<<dim3(256), blk, 0, stream>>>(owb, xidwtb, wprojT, out + 256, wproj_b);
}

// Round 13
// 147.799 us; speedup vs baseline: 1.4025x; 1.0772x over previous
//
#include <hip/hip_runtime.h>
#include <hip/hip_bf16.h>
#include <math.h>

#define WEPS 1e-5f
#define WSCALE 0.125f
#define QSCALE 0.1803368801111244f   // 0.125 * log2(e)

enum { EPI_NONE=0, EPI_BIAS=1, EPI_BN_RELU=2 };

typedef __attribute__((ext_vector_type(8))) short bf16x8;
typedef __attribute__((ext_vector_type(4))) float f32x4;

static __device__ inline unsigned short f2bf(float f) {
    __hip_bfloat16 h = __float2bfloat16(f);
    return *(unsigned short*)&h;
}
// native 2^x (v_exp_f32 computes exp2)
static __device__ inline float exp2_fast(float x) {
    float r;
    asm("v_exp_f32 %0, %1" : "=v"(r) : "v"(x));
    return r;
}
// packed f32x2 -> bf16x2 (lo = a, hi = b)
static __device__ inline unsigned cvt_pk_bf16(float a, float b) {
    unsigned r;
    asm("v_cvt_pk_bf16_f32 %0, %1, %2" : "=v"(r) : "v"(a), "v"(b));
    return r;
}
// async global -> LDS, 16B per lane. LDS dest is wave-uniform base + lane*16;
// global source is per-lane (pre-swizzled). Drained by __syncthreads().
static __device__ inline void gload_lds16(const void* gsrc, void* ldst) {
    __builtin_amdgcn_global_load_lds(
        (const __attribute__((address_space(1))) unsigned int*)gsrc,
        (__attribute__((address_space(3))) unsigned int*)ldst, 16, 0, 0);
}
// XCD-aware chunked swizzle (gridDim.x % 8 == 0)
static __device__ inline int xcd_swizzle_id() {
    int id = blockIdx.x;
    int q = gridDim.x >> 3;
    return (id & 7) * q + (id >> 3);
}

// swizzled LDS 16B fragment read: 128B rows, byte ^= (row&7)<<4
static __device__ inline bf16x8 lds_frag(const unsigned short* base, int row, int inner) {
    int byte = row * 128 + (inner ^ ((row & 7) << 4));
    return *(const bf16x8*)((const char*)base + byte);
}
// swizzled LDS 16B fragment read: 256B rows, byte ^= (row&15)<<4
static __device__ inline bf16x8 lds_frag256(const unsigned short* base, int row, int inner) {
    int byte = row * 256 + (inner ^ ((row & 15) << 4));
    return *(const bf16x8*)((const char*)base + byte);
}

// ================= bf16 MFMA GEMM, 128x128 tile, gload_lds dbuf + XCD swizzle ========
// N must be a multiple of 128 (no col guard). 1D grid = nbx*(M/128).
// Source pre-swizzle: lane l of wave w, chunk it -> row = it*32 + w*8 + (l>>3),
// seg = (l&7)^(l>>3); linear LDS slot (row, l&7) thus holds global seg s^(row&7),
// matching lds_frag's XOR read (rule #21: linear dest + inv-swz source + swz read).
template<int EPI, int OBF16>
__launch_bounds__(256)
__global__ void gemm_bf16(const __hip_bfloat16* __restrict__ A, int lda,
                          const __hip_bfloat16* __restrict__ Bt, int K,
                          void* __restrict__ Cv, int ldc, int N, int nbx,
                          const float* __restrict__ bias,
                          const float* __restrict__ bn_g,
                          const float* __restrict__ bn_b,
                          float oscale)
{
    __shared__ unsigned short As[2][8192];
    __shared__ unsigned short Bs[2][8192];
    const int tid = threadIdx.x;
    const int lane = tid & 63, wv = tid >> 6;
    const int g = lane >> 4, l16 = lane & 15;
    const int wr = wv >> 1, wc = wv & 1;
    const int w = xcd_swizzle_id();
    const int bm = (w / nbx) << 7;
    const int bn = (w % nbx) << 7;

    int aoff[4], boff[4], ldst[4];
    #pragma unroll
    for (int it = 0; it < 4; it++) {
        int row = (it << 5) + (wv << 3) + (lane >> 3);
        int seg = (lane & 7) ^ (lane >> 3);
        aoff[it] = (bm + row) * lda + (seg << 3);
        boff[it] = (bn + row) * K + (seg << 3);
        ldst[it] = (it * 256 + tid) * 16;
    }
    f32x4 acc[4][4];
    #pragma unroll
    for (int i = 0; i < 4; i++)
        #pragma unroll
        for (int j = 0; j < 4; j++)
            #pragma unroll
            for (int r = 0; r < 4; r++) acc[i][j][r] = 0.f;

    // prologue
    #pragma unroll
    for (int it = 0; it < 4; it++) {
        gload_lds16(A + aoff[it], (char*)As[0] + ldst[it]);
        gload_lds16(Bt + boff[it], (char*)Bs[0] + ldst[it]);
    }
    __syncthreads();

    int cur = 0;
    const int niter = K >> 6;
    for (int t = 0; t < niter; t++) {
        if (t + 1 < niter) {
            int kb = (t + 1) << 6;
            #pragma unroll
            for (int it = 0; it < 4; it++) {
                gload_lds16(A + aoff[it] + kb, (char*)As[cur^1] + ldst[it]);
                gload_lds16(Bt + boff[it] + kb, (char*)Bs[cur^1] + ldst[it]);
            }
        }
        #pragma unroll
        for (int ks = 0; ks < 2; ks++) {
            bf16x8 af[4], bfr[4];
            #pragma unroll
            for (int i = 0; i < 4; i++)
                af[i] = lds_frag(As[cur], (wr<<6) + (i<<4) + l16, (ks<<6) + (g<<4));
            #pragma unroll
            for (int j = 0; j < 4; j++)
                bfr[j] = lds_frag(Bs[cur], (wc<<6) + (j<<4) + l16, (ks<<6) + (g<<4));
            #pragma unroll
            for (int i = 0; i < 4; i++)
                #pragma unroll
                for (int j = 0; j < 4; j++)
                    acc[i][j] = __builtin_amdgcn_mfma_f32_16x16x32_bf16(af[i], bfr[j], acc[i][j], 0, 0, 0);
        }
        __syncthreads();     // drains vmcnt (next tile complete) + buf reuse safety
        cur ^= 1;
    }
    const float bn_s = 0.99999500003749968f;
    #pragma unroll
    for (int i = 0; i < 4; i++) {
        int m = bm + (wr<<6) + (i<<4) + (g<<2);
        #pragma unroll
        for (int j = 0; j < 4; j++) {
            int c = bn + (wc<<6) + (j<<4) + l16;
            float bi = (EPI != EPI_NONE) ? bias[c] : 0.f;
            float sc = 1.f, bb = 0.f;
            if (EPI == EPI_BN_RELU) { sc = bn_g[c] * bn_s; bb = bn_b[c]; }
            #pragma unroll
            for (int r = 0; r < 4; r++) {
                float t = acc[i][j][r] * oscale + bi;
                if (EPI == EPI_BN_RELU) t = fmaxf(t * sc + bb, 0.f);
                if (OBF16) ((__hip_bfloat16*)Cv)[(size_t)(m+r)*ldc + c] = __float2bfloat16(t);
                else       ((float*)Cv)[(size_t)(m+r)*ldc + c] = t;
            }
        }
    }
}

// ================= fused head GEMM: xb @ [sqkv|wq|reduce], gload_lds dbuf ===========
// Grid 1152 (1D). bm = w/9, bn = w%9. K=512. B rows 1088..1151 are OOB-by-design:
// they read valid neighboring ws bytes; their acc columns are discarded (c>=1088).
__launch_bounds__(256)
__global__ void gemmX(const __hip_bfloat16* __restrict__ A,
                      const __hip_bfloat16* __restrict__ Bt,
                      __hip_bfloat16* __restrict__ qkvb,
                      __hip_bfloat16* __restrict__ qbw,
                      float* __restrict__ rbuf,
                      const float* __restrict__ red_b,
                      const float* __restrict__ rbn_g,
                      const float* __restrict__ rbn_b)
{
    __shared__ unsigned short As[2][8192];
    __shared__ unsigned short Bs[2][8192];
    const int tid = threadIdx.x;
    const int lane = tid & 63, wv = tid >> 6;
    const int g = lane >> 4, l16 = lane & 15;
    const int wr = wv >> 1, wc = wv & 1;
    const int w = xcd_swizzle_id();
    const int bm = (w / 9) << 7;
    const int bn = (w % 9) << 7;

    int aoff[4], boff[4], ldst[4];
    #pragma unroll
    for (int it = 0; it < 4; it++) {
        int row = (it << 5) + (wv << 3) + (lane >> 3);
        int seg = (lane & 7) ^ (lane >> 3);
        aoff[it] = (bm + row) * 512 + (seg << 3);
        boff[it] = (bn + row) * 512 + (seg << 3);
        ldst[it] = (it * 256 + tid) * 16;
    }
    f32x4 acc[4][4];
    #pragma unroll
    for (int i = 0; i < 4; i++)
        #pragma unroll
        for (int j = 0; j < 4; j++)
            #pragma unroll
            for (int r = 0; r < 4; r++) acc[i][j][r] = 0.f;

    #pragma unroll
    for (int it = 0; it < 4; it++) {
        gload_lds16(A + aoff[it], (char*)As[0] + ldst[it]);
        gload_lds16(Bt + boff[it], (char*)Bs[0] + ldst[it]);
    }
    __syncthreads();

    int cur = 0;
    for (int t = 0; t < 8; t++) {
        if (t < 7) {
            int kb = (t + 1) << 6;
            #pragma unroll
            for (int it = 0; it < 4; it++) {
                gload_lds16(A + aoff[it] + kb, (char*)As[cur^1] + ldst[it]);
                gload_lds16(Bt + boff[it] + kb, (char*)Bs[cur^1] + ldst[it]);
            }
        }
        #pragma unroll
        for (int ks = 0; ks < 2; ks++) {
            bf16x8 af[4], bfr[4];
            #pragma unroll
            for (int i = 0; i < 4; i++)
                af[i] = lds_frag(As[cur], (wr<<6) + (i<<4) + l16, (ks<<6) + (g<<4));
            #pragma unroll
            for (int j = 0; j < 4; j++)
                bfr[j] = lds_frag(Bs[cur], (wc<<6) + (j<<4) + l16, (ks<<6) + (g<<4));
            #pragma unroll
            for (int i = 0; i < 4; i++)
                #pragma unroll
                for (int j = 0; j < 4; j++)
                    acc[i][j] = __builtin_amdgcn_mfma_f32_16x16x32_bf16(af[i], bfr[j], acc[i][j], 0, 0, 0);
        }
        __syncthreads();
        cur ^= 1;
    }
    const float bn_s = 0.99999500003749968f;
    #pragma unroll
    for (int i = 0; i < 4; i++) {
        int m = bm + (wr<<6) + (i<<4) + (g<<2);
        #pragma unroll
        for (int j = 0; j < 4; j++) {
            int c = bn + (wc<<6) + (j<<4) + l16;
            if (c >= 1088) continue;
            if (c < 768) {
                #pragma unroll
                for (int r = 0; r < 4; r++)
                    qkvb[(size_t)(m+r)*768 + c] = __float2bfloat16(acc[i][j][r]);
            } else if (c < 1024) {
                int c2 = c - 768;
                #pragma unroll
                for (int r = 0; r < 4; r++)
                    qbw[(size_t)(m+r)*256 + c2] = __float2bfloat16(acc[i][j][r] * QSCALE);
            } else {
                int c2 = c - 1024;
                float sc = rbn_g[c2] * bn_s, bb = rbn_b[c2], bi = red_b[c2];
                #pragma unroll
                for (int r = 0; r < 4; r++)
                    rbuf[(size_t)(m+r)*64 + c2] = fmaxf((acc[i][j][r] + bi) * sc + bb, 0.f);
            }
        }
    }
}

// ================= kv GEMM, 64x64 tile dbuf (register-staged, proven) ===============
__launch_bounds__(256)
__global__ void gemm64_kv(const __hip_bfloat16* __restrict__ A,
                          const __hip_bfloat16* __restrict__ Bt,
                          __hip_bfloat16* __restrict__ kbo,   // [16][1024][64]
                          __hip_bfloat16* __restrict__ vto,   // [16][64][1024]
                          const float* __restrict__ bias)
{
    __shared__ unsigned short As[2][4096];
    __shared__ unsigned short Bs[2][4096];
    const int tid = threadIdx.x;
    const int lane = tid & 63, wv = tid >> 6;
    const int g = lane >> 4, l16 = lane & 15;
    const int wr = wv >> 1, wc = wv & 1;
    const int bm = blockIdx.y << 6;
    const int bn = blockIdx.x << 6;

    int swb[2];
    const __hip_bfloat16 *Ap[2], *Bp[2];
    #pragma unroll
    for (int it = 0; it < 2; it++) {
        int idx = tid + (it << 8);
        int row = idx >> 3, seg = idx & 7;
        swb[it] = row * 128 + ((seg << 4) ^ ((row & 7) << 4));
        Ap[it] = A  + (size_t)(bm + row) * 256 + (seg << 3);
        Bp[it] = Bt + (size_t)(bn + row) * 256 + (seg << 3);
    }
    f32x4 acc[2][2];
    #pragma unroll
    for (int i = 0; i < 2; i++)
        #pragma unroll
        for (int j = 0; j < 2; j++)
            #pragma unroll
            for (int r = 0; r < 4; r++) acc[i][j][r] = 0.f;

    #pragma unroll
    for (int it = 0; it < 2; it++) {
        *(float4*)((char*)As[0] + swb[it]) = *(const float4*)(Ap[it]);
        *(float4*)((char*)Bs[0] + swb[it]) = *(const float4*)(Bp[it]);
    }
    __syncthreads();

    int cur = 0;
    for (int t = 0; t < 4; t++) {
        float4 ra[2], rb[2];
        const bool has_next = (t < 3);
        if (has_next) {
            #pragma unroll
            for (int it = 0; it < 2; it++) {
                ra[it] = *(const float4*)(Ap[it] + ((t + 1) << 6));
                rb[it] = *(const float4*)(Bp[it] + ((t + 1) << 6));
            }
        }
        #pragma unroll
        for (int ks = 0; ks < 2; ks++) {
            bf16x8 af[2], bfr[2];
            #pragma unroll
            for (int i = 0; i < 2; i++)
                af[i] = lds_frag(As[cur], (wr<<5) + (i<<4) + l16, (ks<<6) + (g<<4));
            #pragma unroll
            for (int j = 0; j < 2; j++)
                bfr[j] = lds_frag(Bs[cur], (wc<<5) + (j<<4) + l16, (ks<<6) + (g<<4));
            #pragma unroll
            for (int i = 0; i < 2; i++)
                #pragma unroll
                for (int j = 0; j < 2; j++)
                    acc[i][j] = __builtin_amdgcn_mfma_f32_16x16x32_bf16(af[i], bfr[j], acc[i][j], 0, 0, 0);
        }
        if (has_next) {
            #pragma unroll
            for (int it = 0; it < 2; it++) {
                *(float4*)((char*)As[cur^1] + swb[it]) = ra[it];
                *(float4*)((char*)Bs[cur^1] + swb[it]) = rb[it];
            }
        }
        __syncthreads();
        cur ^= 1;
    }

    #pragma unroll
    for (int i = 0; i < 2; i++) {
        int m = bm + (wr<<5) + (i<<4) + (g<<2);
        int bimg = m >> 10, tkn0 = m & 1023;
        #pragma unroll
        for (int j = 0; j < 2; j++) {
            int c = bn + (wc<<5) + (j<<4) + l16;
            if (c < 256) {          // K: [bh][token][d]
                int wh = c >> 6, d0 = c & 63;
                __hip_bfloat16* kp = kbo + (((size_t)((bimg<<2)+wh)) << 16) + (size_t)tkn0*64 + d0;
                #pragma unroll
                for (int r = 0; r < 4; r++)
                    kp[r*64] = __float2bfloat16(acc[i][j][r] + bias[c]);
            } else {                // V: [bh][d][token]
                int c2 = c - 256;
                int wh = c2 >> 6, d = c2 & 63;
                float bi = bias[256 + c2];
                ushort4 h;
                h.x = f2bf(acc[i][j][0] + bi);
                h.y = f2bf(acc[i][j][1] + bi);
                h.z = f2bf(acc[i][j][2] + bi);
                h.w = f2bf(acc[i][j][3] + bi);
                *(ushort4*)(vto + (((size_t)((bimg<<2)+wh)) << 16) + (size_t)d*1024 + tkn0) = h;
            }
        }
    }
}

// ================= fused wproj GEMM, 128x128 gload_lds dbuf + XCD swizzle ===========
// Grid 256 (1D); bm = w/2, bn = w%2. K=320: t<4 from A1 (256 wide), t=4 from A2 (64).
__launch_bounds__(256)
__global__ void gemm_wproj(const __hip_bfloat16* __restrict__ A1,
                           const __hip_bfloat16* __restrict__ A2,
                           const __hip_bfloat16* __restrict__ Bt,  // [256][320]
                           float* __restrict__ C,                  // out+256, ldc=512
                           const float* __restrict__ bias)
{
    __shared__ unsigned short As[2][8192];
    __shared__ unsigned short Bs[2][8192];
    const int tid = threadIdx.x;
    const int lane = tid & 63, wv = tid >> 6;
    const int g = lane >> 4, l16 = lane & 15;
    const int wr = wv >> 1, wc = wv & 1;
    const int w = xcd_swizzle_id();
    const int bm = (w >> 1) << 7;
    const int bn = (w & 1) << 7;

    int a1off[4], a2off[4], boff[4], ldst[4];
    #pragma unroll
    for (int it = 0; it < 4; it++) {
        int row = (it << 5) + (wv << 3) + (lane >> 3);
        int seg = (lane & 7) ^ (lane >> 3);
        a1off[it] = (bm + row) * 256 + (seg << 3);
        a2off[it] = (bm + row) * 64 + (seg << 3);
        boff[it]  = (bn + row) * 320 + (seg << 3);
        ldst[it]  = (it * 256 + tid) * 16;
    }
    f32x4 acc[4][4];
    #pragma unroll
    for (int i = 0; i < 4; i++)
        #pragma unroll
        for (int j = 0; j < 4; j++)
            #pragma unroll
            for (int r = 0; r < 4; r++) acc[i][j][r] = 0.f;

    #pragma unroll
    for (int it = 0; it < 4; it++) {
        gload_lds16(A1 + a1off[it], (char*)As[0] + ldst[it]);
        gload_lds16(Bt + boff[it], (char*)Bs[0] + ldst[it]);
    }
    __syncthreads();

    int cur = 0;
    for (int t = 0; t < 5; t++) {
        if (t < 4) {
            int kb = (t + 1) << 6;
            #pragma unroll
            for (int it = 0; it < 4; it++) {
                if (kb < 256)
                    gload_lds16(A1 + a1off[it] + kb, (char*)As[cur^1] + ldst[it]);
                else
                    gload_lds16(A2 + a2off[it], (char*)As[cur^1] + ldst[it]);
                gload_lds16(Bt + boff[it] + kb, (char*)Bs[cur^1] + ldst[it]);
            }
        }
        #pragma unroll
        for (int ks = 0; ks < 2; ks++) {
            bf16x8 af[4], bfr[4];
            #pragma unroll
            for (int i = 0; i < 4; i++)
                af[i] = lds_frag(As[cur], (wr<<6) + (i<<4) + l16, (ks<<6) + (g<<4));
            #pragma unroll
            for (int j = 0; j < 4; j++)
                bfr[j] = lds_frag(Bs[cur], (wc<<6) + (j<<4) + l16, (ks<<6) + (g<<4));
            #pragma unroll
            for (int i = 0; i < 4; i++)
                #pragma unroll
                for (int j = 0; j < 4; j++)
                    acc[i][j] = __builtin_amdgcn_mfma_f32_16x16x32_bf16(af[i], bfr[j], acc[i][j], 0, 0, 0);
        }
        __syncthreads();
        cur ^= 1;
    }
    #pragma unroll
    for (int i = 0; i < 4; i++) {
        int m = bm + (wr<<6) + (i<<4) + (g<<2);
        #pragma unroll
        for (int j = 0; j < 4; j++) {
            int c = bn + (wc<<6) + (j<<4) + l16;
            float bi = bias[c];
            #pragma unroll
            for (int r = 0; r < 4; r++)
                C[(size_t)(m+r)*512 + c] = acc[i][j][r] + bi;
        }
    }
}

// ================= 3x3 conv: bf16 MFMA, 64x64 tile, BK=128, double-buffered =====
__launch_bounds__(256)
__global__ void conv3_mfma(const __hip_bfloat16* __restrict__ Xd,
                           const __hip_bfloat16* __restrict__ Wt,
                           float* __restrict__ C,
                           const float* __restrict__ bias,
                           const float* __restrict__ bn_g,
                           const float* __restrict__ bn_b)
{
    __shared__ unsigned short As[2][8192];
    __shared__ unsigned short Bs[2][8192];
    const int tid = threadIdx.x;
    const int lane = tid & 63, wv = tid >> 6;
    const int g = lane >> 4, l16 = lane & 15;
    const int wr = wv >> 1, wc = wv & 1;
    const int bm = blockIdx.y << 6;
    const int bn = blockIdx.x << 6;

    int srow[4], sseg[4], swb[4];
    #pragma unroll
    for (int it = 0; it < 4; it++) {
        int idx = tid + (it << 8);
        srow[it] = idx >> 4;
        sseg[it] = idx & 15;
        swb[it]  = srow[it] * 256 + ((sseg[it] << 4) ^ ((srow[it] & 15) << 4));
    }
    int abase[4], ay[4], ax[4];
    #pragma unroll
    for (int it = 0; it < 4; it++) {
        int m = bm + srow[it];
        int bimg = m >> 10, s = m & 1023;
        ay[it] = s >> 5; ax[it] = s & 31;
        abase[it] = bimg << 10;
    }

    f32x4 acc[2][2];
    #pragma unroll
    for (int i = 0; i < 2; i++)
        #pragma unroll
        for (int j = 0; j < 2; j++)
            #pragma unroll
            for (int r = 0; r < 4; r++) acc[i][j][r] = 0.f;

    #pragma unroll
    for (int it = 0; it < 4; it++) {
        int y = ay[it] - 1, xx = ax[it] - 1;
        float4 av = make_float4(0.f,0.f,0.f,0.f);
        if ((unsigned)y < 32u && (unsigned)xx < 32u)
            av = *(const float4*)(Xd + ((size_t)(abase[it] + (y<<5) + xx) << 8) + (sseg[it] << 3));
        *(float4*)((char*)As[0] + swb[it]) = av;
        float4 bv = *(const float4*)(Wt + (size_t)(bn + srow[it]) * 2304 + (sseg[it] << 3));
        *(float4*)((char*)Bs[0] + swb[it]) = bv;
    }
    __syncthreads();

    int cur = 0;
    for (int t = 0; t < 18; t++) {
        float4 ra[4], rb[4];
        const bool has_next = (t + 1 < 18);
        if (has_next) {
            int tn = t + 1;
            int tap = tn >> 1;
            int dy = tap / 3 - 1;
            int dx = tap - (tap / 3) * 3 - 1;
            int i0 = (tn & 1) << 7;
            #pragma unroll
            for (int it = 0; it < 4; it++) {
                int y = ay[it] + dy, xx = ax[it] + dx;
                ra[it] = make_float4(0.f,0.f,0.f,0.f);
                if ((unsigned)y < 32u && (unsigned)xx < 32u)
                    ra[it] = *(const float4*)(Xd + ((size_t)(abase[it] + (y<<5) + xx) << 8) + i0 + (sseg[it] << 3));
                rb[it] = *(const float4*)(Wt + (size_t)(bn + srow[it]) * 2304 + tn * 128 + (sseg[it] << 3));
            }
        }
        #pragma unroll
        for (int ks = 0; ks < 4; ks++) {
            bf16x8 af[2], bfr[2];
            #pragma unroll
            for (int i = 0; i < 2; i++)
                af[i] = lds_frag256(As[cur], (wr<<5) + (i<<4) + l16, (ks<<6) + (g<<4));
            #pragma unroll
            for (int j = 0; j < 2; j++)
                bfr[j] = lds_frag256(Bs[cur], (wc<<5) + (j<<4) + l16, (ks<<6) + (g<<4));
            #pragma unroll
            for (int i = 0; i < 2; i++)
                #pragma unroll
                for (int j = 0; j < 2; j++)
                    acc[i][j] = __builtin_amdgcn_mfma_f32_16x16x32_bf16(af[i], bfr[j], acc[i][j], 0, 0, 0);
        }
        if (has_next) {
            #pragma unroll
            for (int it = 0; it < 4; it++) {
                *(float4*)((char*)As[cur^1] + swb[it]) = ra[it];
                *(float4*)((char*)Bs[cur^1] + swb[it]) = rb[it];
            }
        }
        __syncthreads();
        cur ^= 1;
    }

    const float bn_s = 0.99999500003749968f;
    #pragma unroll
    for (int i = 0; i < 2; i++) {
        int m = bm + (wr<<5) + (i<<4) + (g<<2);
        #pragma unroll
        for (int j = 0; j < 2; j++) {
            int c = bn + (wc<<5) + (j<<4) + l16;
            float sc = bn_g[c] * bn_s, bb = bn_b[c], bi = bias[c];
            #pragma unroll
            for (int r = 0; r < 4; r++)
                C[(size_t)(m + r) * 256 + c] = fmaxf((acc[i][j][r] + bi) * sc + bb, 0.f);
        }
    }
}

// ================= merged prep: cvt + 6 weight transposes + conv filter =============
static __device__ inline void tr_task(const float* in, __hip_bfloat16* o,
                                      int K, int N, int nb, int tid)
{
    int idx = nb * 256 + tid;
    int n = idx / K, k = idx - n * K;
    o[idx] = __float2bfloat16(in[(size_t)k * N + n]);
}

__global__ void prep_all(const float* __restrict__ x,
                         const float* __restrict__ sqkv_w, const float* __restrict__ wq_w,
                         const float* __restrict__ reduce_w, const float* __restrict__ sproj_w,
                         const float* __restrict__ wkv_w, const float* __restrict__ wproj_w,
                         const float* __restrict__ filter_w,
                         __hip_bfloat16* __restrict__ xb, __hip_bfloat16* __restrict__ sqkvT,
                         __hip_bfloat16* __restrict__ wqT, __hip_bfloat16* __restrict__ redT,
                         __hip_bfloat16* __restrict__ sprojT, __hip_bfloat16* __restrict__ wkvT,
                         __hip_bfloat16* __restrict__ wprojT, __hip_bfloat16* __restrict__ wt2b)
{
    int bid = blockIdx.x, tid = threadIdx.x;
    if (bid < 8192) {                       // x -> bf16, 4 elems/thread
        int i = bid * 256 + tid;
        float4 v = ((const float4*)x)[i];
        ushort4 h;
        h.x = f2bf(v.x); h.y = f2bf(v.y); h.z = f2bf(v.z); h.w = f2bf(v.w);
        *(ushort4*)(xb + (size_t)i * 4) = h;
        return;
    }
    bid -= 8192;
    if (bid < 1536) { tr_task(sqkv_w, sqkvT, 512, 768, bid, tid); return; }
    bid -= 1536;
    if (bid < 512)  { tr_task(wq_w, wqT, 512, 256, bid, tid); return; }
    bid -= 512;
    if (bid < 128)  { tr_task(reduce_w, redT, 512, 64, bid, tid); return; }
    bid -= 128;
    if (bid < 256)  { tr_task(sproj_w, sprojT, 256, 256, bid, tid); return; }
    bid -= 256;
    if (bid < 512)  { tr_task(wkv_w, wkvT, 256, 512, bid, tid); return; }
    bid -= 512;
    if (bid < 320)  { tr_task(wproj_w, wprojT, 320, 256, bid, tid); return; }
    bid -= 320;
    {   // conv filter: [o][i][tap] -> [o][tap*256+i]
        int oc = bid;
        const float* src = filter_w + (size_t)(oc * 256 + tid) * 9;
        __hip_bfloat16* dst = wt2b + (size_t)oc * 2304 + tid;
        #pragma unroll
        for (int tap = 0; tap < 9; tap++)
            dst[tap * 256] = __float2bfloat16(src[tap]);
    }
}

// ================= window attention (bf16 in/out) =================
__launch_bounds__(256)
__global__ void win_attn(const __hip_bfloat16* __restrict__ qkv,
                         __hip_bfloat16* __restrict__ sa_o)
{
    int gw = blockIdx.x * 4 + (threadIdx.x >> 6);
    int lane = threadIdx.x & 63;
    int b  = gw >> 12;
    int g  = (gw >> 2) & 1023;
    int sh = gw & 3;
    int hg = g >> 5, wg = g & 31;
    float q[4], k[4], v[4];
    int rows[4];
    #pragma unroll
    for (int l = 0; l < 4; l++) {
        int h = (hg << 1) + (l >> 1), w = (wg << 1) + (l & 1);
        int row = (b << 12) + (h << 6) + w;
        rows[l] = row;
        const __hip_bfloat16* p = qkv + (size_t)row * 768 + sh * 64 + lane;
        q[l] = __bfloat162float(p[0]);
        k[l] = __bfloat162float(p[256]);
        v[l] = __bfloat162float(p[512]);
    }
    float s[4][4];
    #pragma unroll
    for (int l = 0; l < 4; l++)
        #pragma unroll
        for (int m = 0; m < 4; m++) s[l][m] = q[l] * k[m];
    #pragma unroll
    for (int off = 32; off > 0; off >>= 1)
        #pragma unroll
        for (int l = 0; l < 4; l++)
            #pragma unroll
            for (int m = 0; m < 4; m++)
                s[l][m] += __shfl_xor(s[l][m], off, 64);
    #pragma unroll
    for (int l = 0; l < 4; l++) {
        float s0 = s[l][0]*WSCALE, s1 = s[l][1]*WSCALE, s2 = s[l][2]*WSCALE, s3 = s[l][3]*WSCALE;
        float mx = fmaxf(fmaxf(s0,s1), fmaxf(s2,s3));
        float p0 = __expf(s0-mx), p1 = __expf(s1-mx), p2 = __expf(s2-mx), p3 = __expf(s3-mx);
        float inv = 1.f / (p0+p1+p2+p3);
        float o = (p0*v[0] + p1*v[1] + p2*v[2] + p3*v[3]) * inv;
        sa_o[(size_t)rows[l] * 256 + sh * 64 + lane] = __float2bfloat16(o);
    }
}

// ================= Haar DWT (fp32 in -> bf16 channel-last) =================
__global__ void dwt_kernel(const float* __restrict__ r, __hip_bfloat16* __restrict__ xd)
{
    int t = blockIdx.x * 256 + threadIdx.x;
    int o = t & 63;
    int x = (t >> 6) & 31;
    int y = (t >> 11) & 31;
    int b = t >> 16;
    const float* rb = r + (b << 18);
    int base = ((y << 1) << 6) + (x << 1);
    float a  = rb[(base     ) * 64 + o];
    float bb = rb[(base +  1) * 64 + o];
    float c  = rb[(base + 64) * 64 + o];
    float d  = rb[(base + 65) * 64 + o];
    float ll = 0.5f*(a+bb+c+d), lh = 0.5f*(a+bb-c-d);
    float hl = 0.5f*(a-bb+c-d), hh = 0.5f*(a-bb-c+d);
    __hip_bfloat16* outp = xd + (((b << 10) + (y << 5) + x) << 8) + o;
    outp[0]   = __float2bfloat16(ll);
    outp[64]  = __float2bfloat16(lh);
    outp[128] = __float2bfloat16(hl);
    outp[192] = __float2bfloat16(hh);
}

// ================= merged LN (rows 0..4095) + IDWT (blocks 4096..5119) =============
__launch_bounds__(256)
__global__ void ln_idwt(const float* __restrict__ X, const float* __restrict__ g,
                        const float* __restrict__ bta, __hip_bfloat16* __restrict__ Y,
                        __hip_bfloat16* __restrict__ xi)
{
    int bid = blockIdx.x;
    int t = threadIdx.x;
    if (bid < 4096) {
        int row = bid;
        float x = X[(size_t)row * 256 + t];
        __shared__ float red[4];
        int wv = t >> 6, ln = t & 63;
        float s = x;
        #pragma unroll
        for (int off = 32; off > 0; off >>= 1) s += __shfl_xor(s, off, 64);
        if (ln == 0) red[wv] = s;
        __syncthreads();
        float m = (red[0]+red[1]+red[2]+red[3]) * (1.f/256.f);
        float d = x - m;
        float s2 = d * d;
        #pragma unroll
        for (int off = 32; off > 0; off >>= 1) s2 += __shfl_xor(s2, off, 64);
        __syncthreads();
        if (ln == 0) red[wv] = s2;
        __syncthreads();
        float var = (red[0]+red[1]+red[2]+red[3]) * (1.f/256.f);
        float inv = 1.f / sqrtf(var + WEPS);
        Y[(size_t)row * 256 + t] = __float2bfloat16(d * inv * g[t] + bta[t]);
        return;
    }
    int tt = (bid - 4096) * 256 + t;
    int o = tt & 63;
    int x = (tt >> 6) & 31;
    int y = (tt >> 11) & 31;
    int b = tt >> 16;
    const float* p = X + (((b << 10) + (y << 5) + x) << 8);
    float ll = p[o], lh = p[64+o], hl = p[128+o], hh = p[192+o];
    float y00 = 0.5f*(ll+lh+hl+hh);
    float y01 = 0.5f*(ll+lh-hl-hh);
    float y10 = 0.5f*(ll-lh+hl-hh);
    float y11 = 0.5f*(ll-lh-hl+hh);
    __hip_bfloat16* ob = xi + ((size_t)b << 18);
    int base = ((y << 1) << 6) + (x << 1);
    ob[(size_t)(base     ) * 64 + o] = __float2bfloat16(y00);
    ob[(size_t)(base +  1) * 64 + o] = __float2bfloat16(y01);
    ob[(size_t)(base + 64) * 64 + o] = __float2bfloat16(y10);
    ob[(size_t)(base + 65) * 64 + o] = __float2bfloat16(y11);
}

// ================= MFMA flash attention: KVBLK=64, native exp2, cvt_pk ==============
__launch_bounds__(256)
__global__ void flash_mfma(const __hip_bfloat16* __restrict__ qb,
                           const __hip_bfloat16* __restrict__ kb,
                           const __hip_bfloat16* __restrict__ vt,
                           __hip_bfloat16* __restrict__ ow)
{
    __shared__ unsigned short Ks[4096];
    __shared__ unsigned short Vs[4096];
    const int tid = threadIdx.x;
    const int wv = tid >> 6;
    const int lane = tid & 63;
    const int g = lane >> 4, q16 = lane & 15;
    const int bh = blockIdx.y;
    const int b = bh >> 2, wh = bh & 3;
    const int qbase = (blockIdx.x << 6) + (wv << 4);

    const __hip_bfloat16* qp = qb + ((size_t)((b << 12) + qbase + q16)) * 256 + wh * 64 + g * 8;
    bf16x8 qf0 = *(const bf16x8*)qp;
    bf16x8 qf1 = *(const bf16x8*)(qp + 32);

    const __hip_bfloat16* kbase = kb + ((size_t)bh << 16);
    const __hip_bfloat16* vbase = vt + ((size_t)bh << 16);

    f32x4 oacc[4];
    #pragma unroll
    for (int dc = 0; dc < 4; dc++)
        #pragma unroll
        for (int r = 0; r < 4; r++) oacc[dc][r] = 0.f;
    float m_cur = -1e30f;
    float lsum_part = 0.f;

    for (int t0 = 0; t0 < 1024; t0 += 64) {
        __syncthreads();
        #pragma unroll
        for (int it = 0; it < 2; it++) {
            int off = (tid << 4) + (it << 12);
            int row = off >> 7;
            int inner = off & 127;
            int wb = row * 128 + (inner ^ ((row & 7) << 4));
            float4 kd = *(const float4*)(kbase + (t0 + row) * 64 + (inner >> 1));
            float4 vd = *(const float4*)(vbase + row * 1024 + t0 + (inner >> 1));
            *(float4*)((char*)Ks + wb) = kd;
            *(float4*)((char*)Vs + wb) = vd;
        }
        __syncthreads();

        f32x4 st[4];
        __builtin_amdgcn_s_setprio(1);
        #pragma unroll
        for (int sub = 0; sub < 4; sub++) {
            #pragma unroll
            for (int r = 0; r < 4; r++) st[sub][r] = 0.f;
            bf16x8 k0 = lds_frag(Ks, sub * 16 + q16, g * 16);
            bf16x8 k1 = lds_frag(Ks, sub * 16 + q16, 64 + g * 16);
            st[sub] = __builtin_amdgcn_mfma_f32_16x16x32_bf16(k0, qf0, st[sub], 0, 0, 0);
            st[sub] = __builtin_amdgcn_mfma_f32_16x16x32_bf16(k1, qf1, st[sub], 0, 0, 0);
        }
        __builtin_amdgcn_s_setprio(0);

        float pmax = -1e30f;
        #pragma unroll
        for (int t = 0; t < 4; t++)
            #pragma unroll
            for (int r = 0; r < 4; r++) pmax = fmaxf(pmax, st[t][r]);
        if (!__all(pmax <= m_cur + 11.5f)) {
            float mx = pmax;
            mx = fmaxf(mx, __shfl_xor(mx, 16, 64));
            mx = fmaxf(mx, __shfl_xor(mx, 32, 64));
            float m_new = fmaxf(m_cur, mx);
            float alpha = exp2_fast(m_cur - m_new);
            lsum_part *= alpha;
            #pragma unroll
            for (int r = 0; r < 4; r++) {
                float sc = __shfl(alpha, (g << 2) + r, 64);
                #pragma unroll
                for (int dc = 0; dc < 4; dc++) oacc[dc][r] *= sc;
            }
            m_cur = m_new;
        }

        float psum = 0.f;
        unsigned pk[4][2];
        #pragma unroll
        for (int t = 0; t < 4; t++) {
            float p0 = exp2_fast(st[t][0] - m_cur), p1 = exp2_fast(st[t][1] - m_cur);
            float p2 = exp2_fast(st[t][2] - m_cur), p3 = exp2_fast(st[t][3] - m_cur);
            psum += (p0 + p1) + (p2 + p3);
            pk[t][0] = cvt_pk_bf16(p0, p1);
            pk[t][1] = cvt_pk_bf16(p2, p3);
        }
        lsum_part += psum;

        bool ghi = (g & 2) != 0;
        unsigned pkA0[2], pkA1[2];
        pkA0[0] = ghi ? pk[1][0] : pk[0][0];
        pkA0[1] = ghi ? pk[1][1] : pk[0][1];
        pkA1[0] = ghi ? pk[3][0] : pk[2][0];
        pkA1[1] = ghi ? pk[3][1] : pk[2][1];
        union { int u[4]; bf16x8 v; } A0, A1;
        #pragma unroll
        for (int c = 0; c < 4; c++) {
            int src = (((2 * g + (c >> 1)) & 3) << 4) | q16;
            A0.u[c] = __shfl((int)pkA0[c & 1], src, 64);
            A1.u[c] = __shfl((int)pkA1[c & 1], src, 64);
        }

        __builtin_amdgcn_s_setprio(1);
        #pragma unroll
        for (int dc = 0; dc < 4; dc++) {
            bf16x8 v0 = lds_frag(Vs, dc * 16 + q16, g * 16);
            bf16x8 v1 = lds_frag(Vs, dc * 16 + q16, 64 + g * 16);
            oacc[dc] = __builtin_amdgcn_mfma_f32_16x16x32_bf16(A0.v, v0, oacc[dc], 0, 0, 0);
            oacc[dc] = __builtin_amdgcn_mfma_f32_16x16x32_bf16(A1.v, v1, oacc[dc], 0, 0, 0);
        }
        __builtin_amdgcn_s_setprio(0);
    }

    lsum_part += __shfl_xor(lsum_part, 16, 64);
    lsum_part += __shfl_xor(lsum_part, 32, 64);
    #pragma unroll
    for (int r = 0; r < 4; r++) {
        float inv = 1.f / __shfl(lsum_part, (g << 2) + r, 64);
        int qrow = (b << 12) + qbase + (g << 2) + r;
        #pragma unroll
        for (int dc = 0; dc < 4; dc++)
            ow[(size_t)qrow * 256 + wh * 64 + dc * 16 + q16] =
                __float2bfloat16(oacc[dc][r] * inv);
    }
}

extern "C" void kernel_launch(void* const* d_in, const int* in_sizes, int n_in,
                              void* d_out, int out_size, void* d_ws, size_t ws_size,
                              hipStream_t stream)
{
    const float* x        = (const float*)d_in[0];
    const float* wq_w     = (const float*)d_in[1];
    const float* kv_ln_g  = (const float*)d_in[2];
    const float* kv_ln_b  = (const float*)d_in[3];
    const float* wkv_w    = (const float*)d_in[4];
    const float* wkv_b    = (const float*)d_in[5];
    const float* wproj_w  = (const float*)d_in[6];
    const float* wproj_b  = (const float*)d_in[7];
    const float* reduce_w = (const float*)d_in[8];
    const float* reduce_b = (const float*)d_in[9];
    const float* rbn_g    = (const float*)d_in[10];
    const float* rbn_b    = (const float*)d_in[11];
    const float* filter_w = (const float*)d_in[12];
    const float* filter_b = (const float*)d_in[13];
    const float* fbn_g    = (const float*)d_in[14];
    const float* fbn_b    = (const float*)d_in[15];
    const float* sqkv_w   = (const float*)d_in[16];
    const float* sproj_w  = (const float*)d_in[17];
    const float* sproj_b  = (const float*)d_in[18];
    float* out = (float*)d_out;
    float* ws  = (float*)d_ws;

    // workspace layout (float units). sqkvT|wqT|redT contiguous = BtAll[1088][512].
    __hip_bfloat16* qkvb  = (__hip_bfloat16*)(ws);             // 12,582,912 bf16
    __hip_bfloat16* owb   = (__hip_bfloat16*)(ws);             // reuse after win_attn
    __hip_bfloat16* sa_ob = (__hip_bfloat16*)(ws + 6291456);   // 4,194,304 bf16
    __hip_bfloat16* xb    = (__hip_bfloat16*)(ws + 8388608);   // 8,388,608 bf16
    __hip_bfloat16* sqkvT = (__hip_bfloat16*)(ws + 12582912);  // 393,216 bf16
    __hip_bfloat16* wqT   = (__hip_bfloat16*)(ws + 12779520);  // 131,072 bf16
    __hip_bfloat16* redT  = (__hip_bfloat16*)(ws + 12845056);  // 32,768 bf16
    __hip_bfloat16* sprojT= (__hip_bfloat16*)(ws + 12861440);  // 65,536 bf16
    __hip_bfloat16* wkvT  = (__hip_bfloat16*)(ws + 12894208);  // 131,072 bf16
    __hip_bfloat16* wprojT= (__hip_bfloat16*)(ws + 13025280);  // 81,920 bf16
    __hip_bfloat16* wt2b  = (__hip_bfloat16*)(ws + 13066240);  // 589,824 bf16
    float* rbuf  = ws + 13361152;                              // 1,048,576 f
    __hip_bfloat16* xd1b  = (__hip_bfloat16*)(ws + 14409728);  // 1,048,576 bf16
    float* xd2   = ws + 14934016;                              // 1,048,576 f
    __hip_bfloat16* kvinb = (__hip_bfloat16*)(ws + 15982592);  // 1,048,576 bf16
    __hip_bfloat16* xidwtb= (__hip_bfloat16*)(ws + 16506880);  // 1,048,576 bf16
    __hip_bfloat16* qbw   = (__hip_bfloat16*)(ws + 17031168);  // 4,194,304 bf16
    __hip_bfloat16* kbb   = (__hip_bfloat16*)(ws + 19128320);  // 1,048,576 bf16
    __hip_bfloat16* vtb   = (__hip_bfloat16*)(ws + 19652608);  // 1,048,576 bf16

    dim3 blk(256);

    // prep: single merged launch
    prep_all<<<dim3(11712), blk, 0, stream>>>(x, sqkv_w, wq_w, reduce_w, sproj_w,
                                              wkv_w, wproj_w, filter_w,
                                              xb, sqkvT, wqT, redT, sprojT, wkvT,
                                              wprojT, wt2b);

    // 1. fused head GEMM (gload_lds dbuf + XCD swizzle, 1152 blocks)
    gemmX<<<dim3(1152), blk, 0, stream>>>(xb, sqkvT, qkvb, qbw, rbuf,
                                          reduce_b, rbn_g, rbn_b);
    // 2. window attention
    win_attn<<<dim3(4096), blk, 0, stream>>>(qkvb, sa_ob);
    // 3. sa_out -> out cols [0,256)  (gload_lds dbuf + XCD swizzle, 256 blocks)
    gemm_bf16<EPI_BIAS,0><<<dim3(256), blk, 0, stream>>>(sa_ob, 256, sprojT, 256, out, 512,
                                                         256, 2, sproj_b, nullptr, nullptr, 1.f);
    // 4. DWT -> bf16
    dwt_kernel<<<dim3(1024), blk, 0, stream>>>(rbuf, xd1b);
    // 5. 3x3 conv MFMA + BN + ReLU -> fp32 xd2
    conv3_mfma<<<dim3(4,64), blk, 0, stream>>>(xd1b, wt2b, xd2, filter_b, fbn_g, fbn_b);
    // 6. layernorm + IDWT (merged)
    ln_idwt<<<dim3(5120), blk, 0, stream>>>(xd2, kv_ln_g, kv_ln_b, kvinb, xidwtb);
    // 7. kv GEMM -> bf16 K + transposed V
    gemm64_kv<<<dim3(8,64), blk, 0, stream>>>(kvinb, wkvT, kbb, vtb, wkv_b);
    // 8. flash attention -> bf16 ow
    flash_mfma<<<dim3(64,16), blk, 0, stream>>>(qbw, kbb, vtb, owb);
    // 9. fused wproj -> out cols [256,512)  (gload_lds dbuf + XCD swizzle, 256 blocks)
    gemm_wproj<<<dim3(256), blk, 0, stream>>>(owb, xidwtb, wprojT, out + 256, wproj_b);
}